// Round 5
// baseline (1326.577 us; speedup 1.0000x reference)
//
#include <hip/hip_runtime.h>
#include <cstdint>

#define D_  2048
#define H_  16
#define HD_ 128
#define FF_ 8192
#define T_  2048
#define B_  2
#define BT_ (B_*T_)
#define NP_ (B_*H_)        // 32 (b,h) pairs
#define CH_ 8              // pairs per attention chunk
#define NCH_ (NP_/CH_)     // 4 chunks
#define QKVLD_ (3*D_)      // fused qkv row stride (6144)

typedef __attribute__((ext_vector_type(8))) _Float16 half8;
typedef __attribute__((ext_vector_type(4))) float   floatx4;

// async global->LDS, 16B per lane; LDS dest = wave-uniform base + lane*16
__device__ __forceinline__ void gl_lds16(const void* g, void* l) {
  __builtin_amdgcn_global_load_lds(
      (const __attribute__((address_space(1))) void*)(uintptr_t)g,
      (__attribute__((address_space(3))) void*)(uintptr_t)l,
      16, 0, 0);
}

// ---------------- weight convert + transpose: W[K][N] f32 -> Wt[N][K] f16 ----
__global__ void wconv_kernel(const float* __restrict__ W, _Float16* __restrict__ Wt,
                             int K, int N) {
  __shared__ float tile[64][33];
  int n0 = blockIdx.x * 32, k0 = blockIdx.y * 64;
  int tx = threadIdx.x, ty = threadIdx.y;   // 32 x 8
#pragma unroll
  for (int r = 0; r < 64; r += 8)
    tile[ty + r][tx] = W[(size_t)(k0 + ty + r) * N + n0 + tx];
  __syncthreads();
#pragma unroll
  for (int r = 0; r < 32; r += 8) {
    float a = tile[tx * 2][ty + r], b = tile[tx * 2 + 1][ty + r];
    union { _Float16 h[2]; unsigned u; } cv;
    cv.h[0] = (_Float16)a; cv.h[1] = (_Float16)b;
    ((unsigned*)(Wt + (size_t)(n0 + ty + r) * K + k0))[tx] = cv.u;
  }
}

// ---------------- rmsnorm: fp32 row -> fp16 row --------------------------------
__global__ void rmsnorm_kernel(const float* __restrict__ x, const float* __restrict__ g,
                               _Float16* __restrict__ out) {
  int row = blockIdx.x, tid = threadIdx.x;
  const float4* xr = (const float4*)(x + (size_t)row * D_);
  float4 v1 = xr[tid], v2 = xr[tid + 256];
  float ss = v1.x*v1.x + v1.y*v1.y + v1.z*v1.z + v1.w*v1.w
           + v2.x*v2.x + v2.y*v2.y + v2.z*v2.z + v2.w*v2.w;
  __shared__ float red[256];
  red[tid] = ss; __syncthreads();
  for (int s = 128; s > 0; s >>= 1) { if (tid < s) red[tid] += red[tid + s]; __syncthreads(); }
  float rs = rsqrtf(red[0] * (1.0f / D_) + 1e-6f);
  float4 ga = ((const float4*)g)[tid], gb = ((const float4*)g)[tid + 256];
  _Float16* orow = out + (size_t)row * D_;
  _Float16 t[4] __attribute__((aligned(8)));
  t[0] = (_Float16)(v1.x * rs * ga.x);
  t[1] = (_Float16)(v1.y * rs * ga.y);
  t[2] = (_Float16)(v1.z * rs * ga.z);
  t[3] = (_Float16)(v1.w * rs * ga.w);
  *(uint2*)(orow + tid * 4) = *(const uint2*)t;
  t[0] = (_Float16)(v2.x * rs * gb.x);
  t[1] = (_Float16)(v2.y * rs * gb.y);
  t[2] = (_Float16)(v2.z * rs * gb.z);
  t[3] = (_Float16)(v2.w * rs * gb.w);
  *(uint2*)(orow + (tid + 256) * 4) = *(const uint2*)t;
}

// ================================================================================
// Dense GEMM C = A @ Bt^T, 256x256 tile, BK=32, 8 waves (2M x 4N), wave tile
// 128x64. 4-slot LDS ring (128 KiB), staged 3 K-tiles ahead via global_load_lds.
// Per K-tile two phases; ds_reads issued ONE PHASE BEFORE their MFMA so the
// compiler's counted lgkmcnt before each MFMA cluster is ~free (operands are a
// full phase old). NO explicit lgkmcnt in the loop. Counted vmcnt once per tile
// (P1). Barriers are asm-with-memory-clobber so stage/reads can't migrate.
//   P0(t): [bar | stageA(t+3) | read afY=af(t,h1) | 16 MFMA afX x bfU -> acc 0..3]
//   P1(t): [vmcnt(6/4/0) | bar | stageB(t+3) | read afX=af(t+1,h0), bfV=bf(t+1)
//           | 16 MFMA afY x bfU -> acc 4..7]
// Ledger: WAR — all reads of slot t-1 are drained by compiler lgkm before
// MFMA@P1(t-1), which precedes bar@P0(t), which precedes stage into (t-1)&3.
// RAW — vmcnt(6)@P1 retires everything older than {A(t+2),B(t+2),A(t+3)}, so
// tile t+1 is landed before any wave reads it after the barrier.
// OUTMODE: 0 -> C f16 = acc; 1 -> C f32 = acc + Res; 2 -> C f32 partial at bz.
// Requires M%256==0, N%256==0, (K/gz)%64==0, K/(32*gz) >= 4, total WGs %8==0.
template<int OUTMODE>
__global__ __launch_bounds__(512, 2) void gemm256(
    const _Float16* __restrict__ A, const _Float16* __restrict__ Bt,
    void* __restrict__ Cv, const float* __restrict__ Res,
    int M, int N, int K, int lda, int ldb, int ldc)
{
  constexpr int ASLOT = 256 * 32;    // f16 elems per ring slot (16 KB)
  constexpr int BSLOT = 256 * 32;
  extern __shared__ _Float16 smem[];
  _Float16* As = smem;               // [4][ASLOT]
  _Float16* Bs = smem + 4 * ASLOT;   // [4][BSLOT]

  // XCD-bijective remap
  const int gx = gridDim.x, gy = gridDim.y, gz = gridDim.z;
  int pid = (blockIdx.z * gy + blockIdx.y) * gx + blockIdx.x;
  const int qch = (gx * gy * gz) >> 3;
  int lid = (pid & 7) * qch + (pid >> 3);
  const int bx = lid % gx; lid /= gx;
  const int by = lid % gy; const int bz = lid / gy;

  const int tid  = threadIdx.x;
  const int lane = tid & 63;
  const int w    = tid >> 6;          // 0..7
  const int wm   = w >> 2;            // 0..1
  const int wn   = w & 3;             // 0..3
  const int l15  = lane & 15, q4 = lane >> 4;
  const int m0   = by * 256;
  const int n0   = bx * 256;
  const int KP   = K / gz;
  const int koff = bz * KP;
  const int NT   = KP >> 5;

  // staging lanes: wave w covers rows [half*128 + w*16, +16), 4 x 16B chunks/row
  const int srow = w * 16 + (lane >> 2);
  const int scol = (((lane & 3) ^ ((lane >> 3) & 3)) << 3);  // pre-swizzled col
  const _Float16* Ag = A  + (size_t)(m0 + srow) * lda + scol + koff;
  const _Float16* Bg = Bt + (size_t)(n0 + srow) * ldb + scol + koff;
  const int ldsW = w * 512;

  // ds_read swizzle: logical chunk q4 lives at physical chunk q4^((row>>1)&3)
  const int chunk = ((q4 ^ ((l15 >> 1) & 3)) << 3);
  const int arow  = wm * 128 + l15;
  const int brow  = wn * 64 + l15;

  floatx4 acc[8][4];
#pragma unroll
  for (int i = 0; i < 8; ++i)
#pragma unroll
    for (int j = 0; j < 4; ++j)
#pragma unroll
      for (int r = 0; r < 4; ++r) acc[i][j][r] = 0.0f;

  auto stageA = [&](int t) {
    const int slot = t & 3;
    gl_lds16(Ag + t * 32,                        As + slot * ASLOT + ldsW);
    gl_lds16(Ag + (size_t)128 * lda + t * 32,    As + slot * ASLOT + 4096 + ldsW);
  };
  auto stageB = [&](int t) {
    const int slot = t & 3;
    gl_lds16(Bg + t * 32,                        Bs + slot * BSLOT + ldsW);
    gl_lds16(Bg + (size_t)128 * ldb + t * 32,    Bs + slot * BSLOT + 4096 + ldsW);
  };
  auto readA = [&](int t, int ih, half8 (&af)[4]) {
    const _Float16* aS = As + (t & 3) * ASLOT + (arow + ih * 64) * 32 + chunk;
#pragma unroll
    for (int i = 0; i < 4; ++i) af[i] = *(const half8*)(aS + i * 16 * 32);
  };
  auto readB = [&](int t, half8 (&bf)[4]) {
    const _Float16* bS = Bs + (t & 3) * BSLOT + brow * 32 + chunk;
#pragma unroll
    for (int j = 0; j < 4; ++j) bf[j] = *(const half8*)(bS + j * 16 * 32);
  };

  half8 afX[4], afY[4], bfU[4], bfV[4];

  auto TILE = [&](int t, half8 (&bCur)[4], half8 (&bNxt)[4]) {
    // -------- P0: MFMA i-half 0 of tile t (operands read last phase) --------
    asm volatile("s_barrier" ::: "memory");
    if (t + 3 < NT) stageA(t + 3);
    readA(t, 1, afY);                       // operands for P1's MFMA
    __builtin_amdgcn_s_setprio(1);
#pragma unroll
    for (int i = 0; i < 4; ++i)
#pragma unroll
      for (int j = 0; j < 4; ++j)
        acc[i][j] = __builtin_amdgcn_mfma_f32_16x16x32_f16(afX[i], bCur[j], acc[i][j], 0, 0, 0);
    __builtin_amdgcn_s_setprio(0);
    // -------- P1: MFMA i-half 1 of tile t --------
    if (t + 3 < NT)      asm volatile("s_waitcnt vmcnt(6)" ::: "memory");
    else if (t + 2 < NT) asm volatile("s_waitcnt vmcnt(4)" ::: "memory");
    else                 asm volatile("s_waitcnt vmcnt(0)" ::: "memory");
    asm volatile("s_barrier" ::: "memory");
    if (t + 3 < NT) stageB(t + 3);
    if (t + 1 < NT) { readA(t + 1, 0, afX); readB(t + 1, bNxt); }
    __builtin_amdgcn_s_setprio(1);
#pragma unroll
    for (int i = 0; i < 4; ++i)
#pragma unroll
      for (int j = 0; j < 4; ++j)
        acc[4 + i][j] = __builtin_amdgcn_mfma_f32_16x16x32_f16(afY[i], bCur[j], acc[4 + i][j], 0, 0, 0);
    __builtin_amdgcn_s_setprio(0);
  };

  // prologue: stage tiles 0..2; tiles 0,1 landed (A2,B2 = 4 ops in flight);
  // pre-read tile 0 half-0 A and B fragments.
  stageA(0); stageB(0); stageA(1); stageB(1); stageA(2); stageB(2);
  asm volatile("s_waitcnt vmcnt(4)" ::: "memory");
  asm volatile("s_barrier" ::: "memory");
  readA(0, 0, afX);
  readB(0, bfU);

  for (int t = 0; t < NT; t += 2) {
    TILE(t,     bfU, bfV);
    TILE(t + 1, bfV, bfU);
  }

  // epilogue: C/D layout col=lane&15, row=(lane>>4)*4+r
  const int crow0 = m0 + wm * 128 + q4 * 4;
  const int ccol0 = n0 + wn * 64 + l15;
#pragma unroll
  for (int i = 0; i < 8; ++i)
#pragma unroll
    for (int j = 0; j < 4; ++j)
#pragma unroll
      for (int r = 0; r < 4; ++r) {
        size_t o = (size_t)(crow0 + i * 16 + r) * ldc + (ccol0 + j * 16);
        if constexpr (OUTMODE == 0)      ((_Float16*)Cv)[o] = (_Float16)acc[i][j][r];
        else if constexpr (OUTMODE == 1) ((float*)Cv)[o] = acc[i][j][r] + Res[o];
        else ((float*)Cv)[(size_t)bz * M * ldc + o] = acc[i][j][r];
      }
}

// ---------------- split-K reduce: out = p0 + p1 + res (all f32) -----------------
__global__ void addred_kernel(const float* __restrict__ parts, const float* __restrict__ res,
                              float* __restrict__ out) {
  size_t i = ((size_t)blockIdx.x * 256 + threadIdx.x) * 4;
  const size_t MN = (size_t)BT_ * D_;
  float4 a = *(const float4*)(parts + i);
  float4 b = *(const float4*)(parts + MN + i);
  float4 r = *(const float4*)(res + i);
  float4 o;
  o.x = a.x + b.x + r.x; o.y = a.y + b.y + r.y;
  o.z = a.z + b.z + r.z; o.w = a.w + b.w + r.w;
  *(float4*)(out + i) = o;
}

// ---------------- old 128x128 MFMA GEMM (attention scores / PV only) ------------
template<int CMODE, int ADDRES, int LOCALS>
__global__ __launch_bounds__(256, 3) void gemm_bt(
    const _Float16* __restrict__ A, const _Float16* __restrict__ Bt,
    void* __restrict__ Cv, const float* __restrict__ Res,
    int M, int N, int K, int lda, int ldb, int ldc, int pair0,
    long long sAd, long long sAm, long long sBd, long long sBm,
    long long sCd, long long sCm)
{
  const int gx = gridDim.x, gy = gridDim.y;
  int pid = (blockIdx.z * gy + blockIdx.y) * gx + blockIdx.x;
  const int qch = (gx * gy * gridDim.z) >> 3;
  int lid = (pid & 7) * qch + (pid >> 3);
  const int bxx = lid % gx; lid /= gx;
  const int byy = lid % gy; const int bzz = lid / gy;

  int zl = bzz;
  int p = pair0 + zl;
  long long aoff = (LOCALS & 1) ? (long long)zl * sAd
                                : (long long)(p >> 4) * sAd + (long long)(p & 15) * sAm;
  long long boff = (long long)(p >> 4) * sBd + (long long)(p & 15) * sBm;
  long long coff = (LOCALS & 2) ? (long long)zl * sCd
                                : (long long)(p >> 4) * sCd + (long long)(p & 15) * sCm;
  const _Float16* Ab = A + (size_t)aoff;
  const _Float16* Bb = Bt + (size_t)boff;
  int m0 = byy * 128, n0 = bxx * 128;
  if (CMODE == 1 && n0 > m0 + 127) return;
  int kmax = K;
  if (CMODE == 2) kmax = min(K, m0 + 128);

  __shared__ __align__(16) _Float16 As[128 * 32];
  __shared__ __align__(16) _Float16 Bs[128 * 32];

  int tid = threadIdx.x;
  int lane = tid & 63;
  int w = tid >> 6;
  int wm = ((tid >> 7) & 1) * 64;
  int wn = ((tid >> 6) & 1) * 64;
  int l15 = lane & 15, q4 = lane >> 4;

  int arow = w * 32;
  int lrow = lane >> 2, lcol = (lane & 3) * 8;
  const _Float16* Ag = Ab + (size_t)(m0 + arow + lrow) * lda + lcol;
  const _Float16* Bg = Bb + (size_t)(n0 + arow + lrow) * ldb + lcol;
  const _Float16* Ag2 = Ag + (size_t)16 * lda;
  const _Float16* Bg2 = Bg + (size_t)16 * ldb;
  _Float16* lA  = &As[arow * 32];
  _Float16* lA2 = &As[(arow + 16) * 32];
  _Float16* lB  = &Bs[arow * 32];
  _Float16* lB2 = &Bs[(arow + 16) * 32];

  floatx4 acc[4][4];
#pragma unroll
  for (int i = 0; i < 4; i++)
#pragma unroll
    for (int j = 0; j < 4; j++)
#pragma unroll
      for (int r = 0; r < 4; r++) acc[i][j][r] = 0.0f;

  for (int k0 = 0; k0 < kmax; k0 += 32) {
    gl_lds16(Ag + k0, lA);
    gl_lds16(Ag2 + k0, lA2);
    gl_lds16(Bg + k0, lB);
    gl_lds16(Bg2 + k0, lB2);
    __syncthreads();
    half8 af[4], bfr[4];
#pragma unroll
    for (int i = 0; i < 4; i++)
      af[i] = *(const half8*)(&As[(wm + i * 16 + l15) * 32 + q4 * 8]);
#pragma unroll
    for (int j = 0; j < 4; j++)
      bfr[j] = *(const half8*)(&Bs[(wn + j * 16 + l15) * 32 + q4 * 8]);
#pragma unroll
    for (int i = 0; i < 4; i++)
#pragma unroll
      for (int j = 0; j < 4; j++)
        acc[i][j] = __builtin_amdgcn_mfma_f32_16x16x32_f16(af[i], bfr[j], acc[i][j], 0, 0, 0);
    __syncthreads();
  }

#pragma unroll
  for (int i = 0; i < 4; i++) {
#pragma unroll
    for (int j = 0; j < 4; j++) {
#pragma unroll
      for (int r = 0; r < 4; r++) {
        int row = m0 + wm + i * 16 + q4 * 4 + r;
        int col = n0 + wn + j * 16 + l15;
        size_t o = (size_t)(coff + (long long)row * ldc + col);
        if (ADDRES) ((float*)Cv)[o] = acc[i][j][r] + Res[o];
        else        ((_Float16*)Cv)[o] = (_Float16)acc[i][j][r];
      }
    }
  }
}

// ---------------- RoPE on fused qkv (q at col 0, k at col D_) -------------------
__global__ void rope_kernel(_Float16* __restrict__ qkv, const void* __restrict__ pos) {
  int gid = blockIdx.x * 256 + threadIdx.x;   // BT_*H_*64 threads
  int d = gid & 63;
  int h = (gid >> 6) & 15;
  int bt = gid >> 10;
  const int* pi = (const int*)pos;
  long long pv = (pi[1] == 0 && pi[2] == 1) ? ((const long long*)pos)[bt]
                                            : (long long)pi[bt];
  float inv = exp2f((float)d * -0.2076205059304601f);  // 10000^(-d/64)
  float ang = (float)pv * inv;
  float s, c;
  sincosf(ang, &s, &c);
  size_t base = (size_t)bt * QKVLD_ + (size_t)h * HD_ + d;
  _Float16* q = qkv;
  _Float16* k = qkv + D_;
  float x1v = (float)q[base], x2v = (float)q[base + 64];
  q[base]      = (_Float16)(x1v * c - x2v * s);
  q[base + 64] = (_Float16)(x2v * c + x1v * s);
  x1v = (float)k[base]; x2v = (float)k[base + 64];
  k[base]      = (_Float16)(x1v * c - x2v * s);
  k[base + 64] = (_Float16)(x2v * c + x1v * s);
}

// ---------------- v[b][t][...] (ld stride) -> vt[(b*H+h)][d][t] -----------------
__global__ void vtrans_kernel(const _Float16* __restrict__ v, _Float16* __restrict__ vt,
                              int ld) {
  __shared__ _Float16 tile[32][33];
  int t0 = blockIdx.x * 32, d0 = blockIdx.y * 32, bh = blockIdx.z;
  int b = bh >> 4, h = bh & 15;
  int tx = threadIdx.x, ty = threadIdx.y;   // 32 x 8
  const _Float16* vb = v + (size_t)b * T_ * ld + (size_t)h * HD_;
#pragma unroll
  for (int r = 0; r < 32; r += 8)
    tile[ty + r][tx] = vb[(size_t)(t0 + ty + r) * ld + d0 + tx];
  __syncthreads();
  _Float16* vo = vt + ((size_t)bh * HD_ + d0) * T_ + t0;
#pragma unroll
  for (int r = 0; r < 32; r += 8)
    vo[(size_t)(ty + r) * T_ + tx] = tile[tx][ty + r];
}

// ---------------- causal softmax over one row of scores (in place) --------------
__global__ void softmax_kernel(_Float16* __restrict__ probs) {
  long long rowid = blockIdx.x;
  int i = (int)(rowid & (T_ - 1));
  _Float16* row = probs + (size_t)rowid * T_;
  int tid = threadIdx.x;
  int j0 = tid * 8;
  uint4 raw = *(const uint4*)(row + j0);
  const _Float16* ph = (const _Float16*)&raw;
  const float scale = 0.08838834764831845f;     // 1/sqrt(128)
  float vals[8];
  float mx = -1e30f;
#pragma unroll
  for (int l = 0; l < 8; l++) {
    float v = (j0 + l <= i) ? (float)ph[l] * scale : -1e30f;
    vals[l] = v; mx = fmaxf(mx, v);
  }
  __shared__ float red[256];
  red[tid] = mx; __syncthreads();
  for (int s = 128; s > 0; s >>= 1) { if (tid < s) red[tid] = fmaxf(red[tid], red[tid + s]); __syncthreads(); }
  float M = red[0]; __syncthreads();
  float se = 0.f;
#pragma unroll
  for (int l = 0; l < 8; l++) { float e = __expf(vals[l] - M); vals[l] = e; se += e; }
  red[tid] = se; __syncthreads();
  for (int s = 128; s > 0; s >>= 1) { if (tid < s) red[tid] += red[tid + s]; __syncthreads(); }
  float inv = 1.0f / red[0];
  _Float16 t[8] __attribute__((aligned(16)));
#pragma unroll
  for (int l = 0; l < 8; l++) t[l] = (j0 + l <= i) ? (_Float16)(vals[l] * inv) : (_Float16)0.f;
  *(uint4*)(row + j0) = *(const uint4*)t;
}

// ---------------- hu = silu(gate) * up  (written over gate) ---------------------
__global__ void silumul_kernel(_Float16* __restrict__ gate, const _Float16* __restrict__ up) {
  size_t idx = ((size_t)blockIdx.x * 256 + threadIdx.x) * 8;
  uint4 gr = *(const uint4*)(gate + idx);
  uint4 ur = *(const uint4*)(up + idx);
  const _Float16* gh = (const _Float16*)&gr;
  const _Float16* uh = (const _Float16*)&ur;
  _Float16 t[8] __attribute__((aligned(16)));
#pragma unroll
  for (int l = 0; l < 8; l++) {
    float x = (float)gh[l];
    float s = x / (1.0f + __expf(-x));
    t[l] = (_Float16)(s * (float)uh[l]);
  }
  *(uint4*)(gate + idx) = *(const uint4*)t;
}

// ================================================================================
extern "C" void kernel_launch(void* const* d_in, const int* in_sizes, int n_in,
                              void* d_out, int out_size, void* d_ws, size_t ws_size,
                              hipStream_t stream) {
  (void)in_sizes; (void)n_in; (void)out_size;
  const float* x   = (const float*)d_in[0];
  const void*  pos = d_in[1];
  const float* W[7] = { (const float*)d_in[2], (const float*)d_in[3],
                        (const float*)d_in[4], (const float*)d_in[5],
                        (const float*)d_in[6], (const float*)d_in[7],
                        (const float*)d_in[8] };              // q k v o g u d
  const float* g1  = (const float*)d_in[9];
  const float* g2  = (const float*)d_in[10];
  float* out = (float*)d_out;

  const int wk[7] = { D_, D_, D_, D_, D_, D_, FF_ };
  const int wn[7] = { D_, D_, D_, D_, FF_, FF_, D_ };

  char* p = (char*)d_ws;
  auto carve = [&](size_t bytes) { char* r = p; p += (bytes + 255) & ~(size_t)255; return r; };

  _Float16* probs = (_Float16*)carve((size_t)CH_ * T_ * T_ * 2);   // 64 MB; later: gate
  const size_t FLAT_NEED = (size_t)336 * 1024 * 1024;
  bool flat = ws_size >= FLAT_NEED;
  _Float16* w16[7];
  if (flat) {
    // q,k,v carved contiguously -> fused QKV weight matrix [6144][2048]
    for (int i = 0; i < 7; i++) w16[i] = (_Float16*)carve((size_t)wk[i] * wn[i] * 2);
  } else {
    _Float16* wslot = (_Float16*)carve((size_t)D_ * FF_ * 2);      // 32 MB slot
    w16[0] = wslot;
    w16[1] = wslot + (size_t)D_ * D_;
    w16[2] = wslot + (size_t)2 * D_ * D_;
    w16[3] = w16[4] = w16[5] = w16[6] = wslot;
  }
  _Float16* qkv = (_Float16*)carve((size_t)BT_ * QKVLD_ * 2);  // 48 MB
  _Float16* ob  = (_Float16*)carve((size_t)BT_ * D_ * 2);      // 16 MB (contig after qkv)
  _Float16* xn  = (_Float16*)carve((size_t)BT_ * D_ * 2);      // 16 MB; later: hb
  _Float16* vt  = (_Float16*)carve((size_t)BT_ * D_ * 2);      // 16 MB
  float*    x1  = (float*)   carve((size_t)BT_ * D_ * 4);      // 32 MB
  _Float16* gate = probs;        // 64 MB region, dead after PV
  _Float16* up   = qkv;          // spans qkv(48)+ob(16): both dead after Wo GEMM
  _Float16* hb   = xn;
  float* dparts = (float*)qkv;   // Wd split-K partials (2 x 32 MB); up dead by then

  dim3 b328(32, 8);
  auto conv = [&](int i) {
    wconv_kernel<<<dim3(wn[i] / 32, wk[i] / 64), b328, 0, stream>>>(W[i], w16[i], wk[i], wn[i]);
  };
  if (flat) for (int i = 0; i < 7; i++) conv(i);

  // xn = rmsnorm(x, g1)
  rmsnorm_kernel<<<BT_, 256, 0, stream>>>(x, g1, xn);

  // fused qkv projection: [BT][6144] = xn @ [Wq;Wk;Wv]^T   (384 WGs)
  if (!flat) { conv(0); conv(1); conv(2); }
  gemm256<0><<<dim3(QKVLD_ / 256, BT_ / 256, 1), 512, 131072, stream>>>(
      xn, w16[0], qkv, nullptr, BT_, QKVLD_, D_, D_, D_, QKVLD_);

  // rope(q, k) in fused layout
  rope_kernel<<<(BT_ * H_ * 64) / 256, 256, 0, stream>>>(qkv, pos);

  // v transpose per head: vt[(b*H+h)][d][t]
  vtrans_kernel<<<dim3(T_ / 32, HD_ / 32, NP_), b328, 0, stream>>>(qkv + 2 * D_, vt, QKVLD_);

  // attention in chunks of CH_ (b,h) pairs (old 128x128 kernel: small K)
  for (int c = 0; c < NCH_; c++) {
    gemm_bt<1, 0, 2><<<dim3(T_ / 128, T_ / 128, CH_), 256, 0, stream>>>(
        qkv, qkv + D_, probs, nullptr, T_, T_, HD_, QKVLD_, QKVLD_, T_, c * CH_,
        (long long)T_ * QKVLD_, HD_, (long long)T_ * QKVLD_, HD_,
        (long long)T_ * T_, 0);
    softmax_kernel<<<CH_ * T_, 256, 0, stream>>>(probs);
    gemm_bt<2, 0, 1><<<dim3(1, T_ / 128, CH_), 256, 0, stream>>>(
        probs, vt, ob, nullptr, T_, HD_, T_, T_, T_, D_, c * CH_,
        (long long)T_ * T_, 0,
        16LL * HD_ * T_, (long long)HD_ * T_,
        (long long)T_ * D_, HD_);
  }

  // x1 = x + o @ Wo   (128 WGs, direct residual epilogue)
  if (!flat) conv(3);
  gemm256<1><<<dim3(D_ / 256, BT_ / 256, 1), 512, 131072, stream>>>(
      ob, w16[3], x1, x, BT_, D_, D_, D_, D_, D_);

  // h = rmsnorm(x1, g2)
  rmsnorm_kernel<<<BT_, 256, 0, stream>>>(x1, g2, hb);

  // gate = h @ Wg ; up = h @ Wu   (512 WGs each)
  if (!flat) conv(4);
  gemm256<0><<<dim3(FF_ / 256, BT_ / 256, 1), 512, 131072, stream>>>(
      hb, w16[4], gate, nullptr, BT_, FF_, D_, D_, D_, FF_);
  if (!flat) conv(5);
  gemm256<0><<<dim3(FF_ / 256, BT_ / 256, 1), 512, 131072, stream>>>(
      hb, w16[5], up, nullptr, BT_, FF_, D_, D_, D_, FF_);

  // hu = silu(gate) * up  (in gate)
  silumul_kernel<<<(BT_ * FF_ / 8) / 256, 256, 0, stream>>>(gate, up);

  // Wd split-K=2: partials = hu @ Wd (per half-K), then out = p0 + p1 + x1
  if (!flat) conv(6);
  gemm256<2><<<dim3(D_ / 256, BT_ / 256, 2), 512, 131072, stream>>>(
      gate, w16[6], dparts, nullptr, BT_, D_, FF_, FF_, FF_, D_);
  addred_kernel<<<(BT_ * D_ / 4) / 256, 256, 0, stream>>>(dparts, x1, out);
}

// Round 6
// 1292.873 us; speedup vs baseline: 1.0261x; 1.0261x over previous
//
#include <hip/hip_runtime.h>
#include <cstdint>

#define D_  2048
#define H_  16
#define HD_ 128
#define FF_ 8192
#define T_  2048
#define B_  2
#define BT_ (B_*T_)
#define NP_ (B_*H_)        // 32 (b,h) pairs
#define CH_ 8              // pairs per attention chunk
#define NCH_ (NP_/CH_)     // 4 chunks
#define QKVLD_ (3*D_)      // fused qkv row stride (6144)

typedef __attribute__((ext_vector_type(8))) _Float16 half8;
typedef __attribute__((ext_vector_type(4))) float   floatx4;

// async global->LDS, 16B per lane; LDS dest = wave-uniform base + lane*16
__device__ __forceinline__ void gl_lds16(const void* g, void* l) {
  __builtin_amdgcn_global_load_lds(
      (const __attribute__((address_space(1))) void*)(uintptr_t)g,
      (__attribute__((address_space(3))) void*)(uintptr_t)l,
      16, 0, 0);
}

// ---------------- weight convert + transpose: W[K][N] f32 -> Wt[N][K] f16 ----
__global__ void wconv_kernel(const float* __restrict__ W, _Float16* __restrict__ Wt,
                             int K, int N) {
  __shared__ float tile[64][33];
  int n0 = blockIdx.x * 32, k0 = blockIdx.y * 64;
  int tx = threadIdx.x, ty = threadIdx.y;   // 32 x 8
#pragma unroll
  for (int r = 0; r < 64; r += 8)
    tile[ty + r][tx] = W[(size_t)(k0 + ty + r) * N + n0 + tx];
  __syncthreads();
#pragma unroll
  for (int r = 0; r < 32; r += 8) {
    float a = tile[tx * 2][ty + r], b = tile[tx * 2 + 1][ty + r];
    union { _Float16 h[2]; unsigned u; } cv;
    cv.h[0] = (_Float16)a; cv.h[1] = (_Float16)b;
    ((unsigned*)(Wt + (size_t)(n0 + ty + r) * K + k0))[tx] = cv.u;
  }
}

// ---------------- rmsnorm: fp32 row -> fp16 row --------------------------------
__global__ void rmsnorm_kernel(const float* __restrict__ x, const float* __restrict__ g,
                               _Float16* __restrict__ out) {
  int row = blockIdx.x, tid = threadIdx.x;
  const float4* xr = (const float4*)(x + (size_t)row * D_);
  float4 v1 = xr[tid], v2 = xr[tid + 256];
  float ss = v1.x*v1.x + v1.y*v1.y + v1.z*v1.z + v1.w*v1.w
           + v2.x*v2.x + v2.y*v2.y + v2.z*v2.z + v2.w*v2.w;
  __shared__ float red[256];
  red[tid] = ss; __syncthreads();
  for (int s = 128; s > 0; s >>= 1) { if (tid < s) red[tid] += red[tid + s]; __syncthreads(); }
  float rs = rsqrtf(red[0] * (1.0f / D_) + 1e-6f);
  float4 ga = ((const float4*)g)[tid], gb = ((const float4*)g)[tid + 256];
  _Float16* orow = out + (size_t)row * D_;
  _Float16 t[4] __attribute__((aligned(8)));
  t[0] = (_Float16)(v1.x * rs * ga.x);
  t[1] = (_Float16)(v1.y * rs * ga.y);
  t[2] = (_Float16)(v1.z * rs * ga.z);
  t[3] = (_Float16)(v1.w * rs * ga.w);
  *(uint2*)(orow + tid * 4) = *(const uint2*)t;
  t[0] = (_Float16)(v2.x * rs * gb.x);
  t[1] = (_Float16)(v2.y * rs * gb.y);
  t[2] = (_Float16)(v2.z * rs * gb.z);
  t[3] = (_Float16)(v2.w * rs * gb.w);
  *(uint2*)(orow + (tid + 256) * 4) = *(const uint2*)t;
}

// ================================================================================
// m201-style 8-phase GEMM, C = A @ Bt^T. 256x256 tile, BK=64, 8 waves (2Mx4N),
// wave tile 128x64. LDS: 2-slot double buffer { A[256][64], B[256][64] } f16 =
// 128 KiB. 4 phases per K-tile; phase q computes C row-blocks {2q,2q+1} over the
// FULL K=64 (16 MFMA). Phase shape (m201): {ds-reads | stage 1 half-tile |
// [lgkm(8) if 12 reads] | barrier | lgkmcnt(0)+sched_barrier | setprio1 |
// 16 MFMA | setprio0 | [vmcnt at phase 4] | barrier}.
// Reads/phase: Ph1 = 12 (all 8 B-frags + A-quad0), Ph2-4 = 4 (A-quad).
// Stage/phase (1 half-tile = 2 gl_lds16): Ph1:A0(t+1) Ph2:A1(t+1)
// Ph3:B0(t+2) Ph4:B1(t+2).  WAR ledger: A(t+1) overwrites A(t-1), whose last
// read (Ph4(t-1)) is lgkm-drained before Ph4(t-1)'s closing barrier, which
// precedes Ph1(t)'s stage issue. B(t+2) overwrites B(t), last read Ph1(t),
// drained before Ph1's MFMA/barrier, precedes Ph3(t). RAW: end-of-tile
// vmcnt(4) keeps only B0,B1(t+2) in flight -> tile t+1 fully landed before its
// Ph1 reads. Prologue stages t0 fully + B0,B1(t1), vmcnt(4).
// Swizzle (0-conflict family): phys 16B-chunk = logical ^ (row&7), applied on
// the pre-swizzled global source column and the ds_read address.
// OUTMODE: 0 -> C f16 = acc; 1 -> C f32 = acc + Res; 2 -> C f32 partial at bz.
// Requires M%256==0, N%256==0, (K/gz)%64==0, K/(64*gz) >= 2, total WGs %8==0.
template<int OUTMODE>
__global__ __launch_bounds__(512, 2) void gemm256(
    const _Float16* __restrict__ A, const _Float16* __restrict__ Bt,
    void* __restrict__ Cv, const float* __restrict__ Res,
    int M, int N, int K, int lda, int ldb, int ldc)
{
  constexpr int SLOT = 256 * 64;     // f16 elems per matrix per slot (32 KB)
  extern __shared__ _Float16 smem[];
  _Float16* As = smem;               // [2][SLOT]
  _Float16* Bs = smem + 2 * SLOT;    // [2][SLOT]

  // XCD-bijective remap
  const int gx = gridDim.x, gy = gridDim.y, gz = gridDim.z;
  int pid = (blockIdx.z * gy + blockIdx.y) * gx + blockIdx.x;
  const int qch = (gx * gy * gz) >> 3;
  int lid = (pid & 7) * qch + (pid >> 3);
  const int bx = lid % gx; lid /= gx;
  const int by = lid % gy; const int bz = lid / gy;

  const int tid  = threadIdx.x;
  const int lane = tid & 63;
  const int w    = tid >> 6;          // 0..7
  const int wm   = w >> 2;            // 0..1
  const int wn   = w & 3;             // 0..3
  const int l15  = lane & 15, q4 = lane >> 4;
  const int m0   = by * 256;
  const int n0   = bx * 256;
  const int KP   = K / gz;
  const int koff = bz * KP;
  const int NT   = KP >> 6;           // K-tiles of 64

  // staging: lane L covers row (seg + L>>3), phys chunk (L&7); source column
  // pre-swizzled so LDS phys chunk p of row r holds logical chunk p^(r&7).
  const int srow8  = lane >> 3;                                   // 0..7
  const int schunk = (((lane & 7) ^ (srow8 & 7)) << 3);           // f16 offset
  const _Float16* Ag = A  + (size_t)(m0 + w * 8 + srow8) * lda + schunk + koff;
  const _Float16* Bg = Bt + (size_t)(n0 + w * 8 + srow8) * ldb + schunk + koff;
  const int ldsW = w * 512;           // wave's 1KB segment within an 8KB seg-block

  // ds_read: logical chunk c at row r lives at phys c^(r&7); r&7 == l15&7.
  const int c0     = ((q4 ^ (l15 & 7)) << 3);     // kk=0 chunk offset (elems)
  const int arow_e = (wm * 128 + l15) * 64;
  const int brow_e = (wn * 64 + l15) * 64;

  floatx4 acc[8][4];
#pragma unroll
  for (int i = 0; i < 8; ++i)
#pragma unroll
    for (int j = 0; j < 4; ++j)
#pragma unroll
      for (int r = 0; r < 4; ++r) acc[i][j][r] = 0.0f;

  auto stA = [&](int t, int h, int s) {
    gl_lds16(Ag + (size_t)(h * 128 + s * 64) * lda + t * 64,
             As + (t & 1) * SLOT + h * 8192 + s * 4096 + ldsW);
  };
  auto stB = [&](int t, int h, int s) {
    gl_lds16(Bg + (size_t)(h * 128 + s * 64) * ldb + t * 64,
             Bs + (t & 1) * SLOT + h * 8192 + s * 4096 + ldsW);
  };

  half8 bf[2][4];                     // [kk][j]
  half8 af0[4], af1[4];               // quad frags: [i2*2+kk]

#define SB0   __builtin_amdgcn_sched_barrier(0)
#define BARR  __builtin_amdgcn_s_barrier()
#define LGKM0 asm volatile("s_waitcnt lgkmcnt(0)" ::: "memory")

#define RD_B8(bSl)                                                          \
  { _Pragma("unroll")                                                       \
    for (int j = 0; j < 4; ++j) {                                           \
      bf[0][j] = *(const half8*)((bSl) + brow_e + j * 1024 + c0);           \
      bf[1][j] = *(const half8*)((bSl) + brow_e + j * 1024 + (c0 ^ 32));    \
    } }
#define RD_A4(aSl, q, af)                                                   \
  { _Pragma("unroll")                                                       \
    for (int i2 = 0; i2 < 2; ++i2) {                                        \
      af[i2*2+0] = *(const half8*)((aSl) + arow_e + ((q)*2+i2) * 1024 + c0);        \
      af[i2*2+1] = *(const half8*)((aSl) + arow_e + ((q)*2+i2) * 1024 + (c0 ^ 32)); \
    } }
#define MFMA_Q(q, af)                                                       \
  { _Pragma("unroll")                                                       \
    for (int kk = 0; kk < 2; ++kk)                                          \
      _Pragma("unroll")                                                     \
      for (int i2 = 0; i2 < 2; ++i2)                                        \
        _Pragma("unroll")                                                   \
        for (int j = 0; j < 4; ++j)                                         \
          acc[(q)*2+i2][j] = __builtin_amdgcn_mfma_f32_16x16x32_f16(        \
              af[i2*2+kk], bf[kk][j], acc[(q)*2+i2][j], 0, 0, 0);           \
  }

  // prologue: tile0 fully + B halves of tile1; vmcnt(4) -> tile0 landed.
  stA(0, 0, 0); stA(0, 0, 1); stA(0, 1, 0); stA(0, 1, 1);
  stB(0, 0, 0); stB(0, 0, 1); stB(0, 1, 0); stB(0, 1, 1);
  if (NT > 1) {
    stB(1, 0, 0); stB(1, 0, 1); stB(1, 1, 0); stB(1, 1, 1);
    asm volatile("s_waitcnt vmcnt(4)" ::: "memory");
  } else {
    asm volatile("s_waitcnt vmcnt(0)" ::: "memory");
  }
  BARR;

  for (int t = 0; t < NT; ++t) {
    const _Float16* aSl = As + (t & 1) * SLOT;
    const _Float16* bSl = Bs + (t & 1) * SLOT;
    const bool s1 = (t + 1 < NT), s2 = (t + 2 < NT);
    // ---- Ph1: all B + A-quad0 ----
    RD_B8(bSl); RD_A4(aSl, 0, af0);
    if (s1) { stA(t + 1, 0, 0); stA(t + 1, 0, 1); }
    asm volatile("s_waitcnt lgkmcnt(8)" ::: "memory");
    SB0; BARR; LGKM0; SB0;
    __builtin_amdgcn_s_setprio(1); MFMA_Q(0, af0); __builtin_amdgcn_s_setprio(0);
    SB0; BARR;
    // ---- Ph2: A-quad1 ----
    RD_A4(aSl, 1, af1);
    if (s1) { stA(t + 1, 1, 0); stA(t + 1, 1, 1); }
    SB0; BARR; LGKM0; SB0;
    __builtin_amdgcn_s_setprio(1); MFMA_Q(1, af1); __builtin_amdgcn_s_setprio(0);
    SB0; BARR;
    // ---- Ph3: A-quad2 ----
    RD_A4(aSl, 2, af0);
    if (s2) { stB(t + 2, 0, 0); stB(t + 2, 0, 1); }
    SB0; BARR; LGKM0; SB0;
    __builtin_amdgcn_s_setprio(1); MFMA_Q(2, af0); __builtin_amdgcn_s_setprio(0);
    SB0; BARR;
    // ---- Ph4: A-quad3 ----
    RD_A4(aSl, 3, af1);
    if (s2) { stB(t + 2, 1, 0); stB(t + 2, 1, 1); }
    SB0; BARR; LGKM0; SB0;
    __builtin_amdgcn_s_setprio(1); MFMA_Q(3, af1); __builtin_amdgcn_s_setprio(0);
    SB0;
    if (s2)      asm volatile("s_waitcnt vmcnt(4)" ::: "memory");
    else if (s1) asm volatile("s_waitcnt vmcnt(0)" ::: "memory");
    BARR;
  }

#undef SB0
#undef BARR
#undef LGKM0
#undef RD_B8
#undef RD_A4
#undef MFMA_Q

  // epilogue: C/D layout col=lane&15, row=(lane>>4)*4+r
  const int crow0 = m0 + wm * 128 + q4 * 4;
  const int ccol0 = n0 + wn * 64 + l15;
#pragma unroll
  for (int i = 0; i < 8; ++i)
#pragma unroll
    for (int j = 0; j < 4; ++j)
#pragma unroll
      for (int r = 0; r < 4; ++r) {
        size_t o = (size_t)(crow0 + i * 16 + r) * ldc + (ccol0 + j * 16);
        if constexpr (OUTMODE == 0)      ((_Float16*)Cv)[o] = (_Float16)acc[i][j][r];
        else if constexpr (OUTMODE == 1) ((float*)Cv)[o] = acc[i][j][r] + Res[o];
        else ((float*)Cv)[(size_t)bz * M * ldc + o] = acc[i][j][r];
      }
}

// ---------------- split-K reduce: out = p0 + p1 + res (all f32) -----------------
__global__ void addred_kernel(const float* __restrict__ parts, const float* __restrict__ res,
                              float* __restrict__ out) {
  size_t i = ((size_t)blockIdx.x * 256 + threadIdx.x) * 4;
  const size_t MN = (size_t)BT_ * D_;
  float4 a = *(const float4*)(parts + i);
  float4 b = *(const float4*)(parts + MN + i);
  float4 r = *(const float4*)(res + i);
  float4 o;
  o.x = a.x + b.x + r.x; o.y = a.y + b.y + r.y;
  o.z = a.z + b.z + r.z; o.w = a.w + b.w + r.w;
  *(float4*)(out + i) = o;
}

// ---------------- old 128x128 MFMA GEMM (attention scores / PV only) ------------
template<int CMODE, int ADDRES, int LOCALS>
__global__ __launch_bounds__(256, 3) void gemm_bt(
    const _Float16* __restrict__ A, const _Float16* __restrict__ Bt,
    void* __restrict__ Cv, const float* __restrict__ Res,
    int M, int N, int K, int lda, int ldb, int ldc, int pair0,
    long long sAd, long long sAm, long long sBd, long long sBm,
    long long sCd, long long sCm)
{
  const int gx = gridDim.x, gy = gridDim.y;
  int pid = (blockIdx.z * gy + blockIdx.y) * gx + blockIdx.x;
  const int qch = (gx * gy * gridDim.z) >> 3;
  int lid = (pid & 7) * qch + (pid >> 3);
  const int bxx = lid % gx; lid /= gx;
  const int byy = lid % gy; const int bzz = lid / gy;

  int zl = bzz;
  int p = pair0 + zl;
  long long aoff = (LOCALS & 1) ? (long long)zl * sAd
                                : (long long)(p >> 4) * sAd + (long long)(p & 15) * sAm;
  long long boff = (long long)(p >> 4) * sBd + (long long)(p & 15) * sBm;
  long long coff = (LOCALS & 2) ? (long long)zl * sCd
                                : (long long)(p >> 4) * sCd + (long long)(p & 15) * sCm;
  const _Float16* Ab = A + (size_t)aoff;
  const _Float16* Bb = Bt + (size_t)boff;
  int m0 = byy * 128, n0 = bxx * 128;
  if (CMODE == 1 && n0 > m0 + 127) return;
  int kmax = K;
  if (CMODE == 2) kmax = min(K, m0 + 128);

  __shared__ __align__(16) _Float16 As[128 * 32];
  __shared__ __align__(16) _Float16 Bs[128 * 32];

  int tid = threadIdx.x;
  int lane = tid & 63;
  int w = tid >> 6;
  int wm = ((tid >> 7) & 1) * 64;
  int wn = ((tid >> 6) & 1) * 64;
  int l15 = lane & 15, q4 = lane >> 4;

  int arow = w * 32;
  int lrow = lane >> 2, lcol = (lane & 3) * 8;
  const _Float16* Ag = Ab + (size_t)(m0 + arow + lrow) * lda + lcol;
  const _Float16* Bg = Bb + (size_t)(n0 + arow + lrow) * ldb + lcol;
  const _Float16* Ag2 = Ag + (size_t)16 * lda;
  const _Float16* Bg2 = Bg + (size_t)16 * ldb;
  _Float16* lA  = &As[arow * 32];
  _Float16* lA2 = &As[(arow + 16) * 32];
  _Float16* lB  = &Bs[arow * 32];
  _Float16* lB2 = &Bs[(arow + 16) * 32];

  floatx4 acc[4][4];
#pragma unroll
  for (int i = 0; i < 4; i++)
#pragma unroll
    for (int j = 0; j < 4; j++)
#pragma unroll
      for (int r = 0; r < 4; r++) acc[i][j][r] = 0.0f;

  for (int k0 = 0; k0 < kmax; k0 += 32) {
    gl_lds16(Ag + k0, lA);
    gl_lds16(Ag2 + k0, lA2);
    gl_lds16(Bg + k0, lB);
    gl_lds16(Bg2 + k0, lB2);
    __syncthreads();
    half8 af[4], bfr[4];
#pragma unroll
    for (int i = 0; i < 4; i++)
      af[i] = *(const half8*)(&As[(wm + i * 16 + l15) * 32 + q4 * 8]);
#pragma unroll
    for (int j = 0; j < 4; j++)
      bfr[j] = *(const half8*)(&Bs[(wn + j * 16 + l15) * 32 + q4 * 8]);
#pragma unroll
    for (int i = 0; i < 4; i++)
#pragma unroll
      for (int j = 0; j < 4; j++)
        acc[i][j] = __builtin_amdgcn_mfma_f32_16x16x32_f16(af[i], bfr[j], acc[i][j], 0, 0, 0);
    __syncthreads();
  }

#pragma unroll
  for (int i = 0; i < 4; i++) {
#pragma unroll
    for (int j = 0; j < 4; j++) {
#pragma unroll
      for (int r = 0; r < 4; r++) {
        int row = m0 + wm + i * 16 + q4 * 4 + r;
        int col = n0 + wn + j * 16 + l15;
        size_t o = (size_t)(coff + (long long)row * ldc + col);
        if (ADDRES) ((float*)Cv)[o] = acc[i][j][r] + Res[o];
        else        ((_Float16*)Cv)[o] = (_Float16)acc[i][j][r];
      }
    }
  }
}

// ---------------- RoPE on fused qkv (q at col 0, k at col D_) -------------------
__global__ void rope_kernel(_Float16* __restrict__ qkv, const void* __restrict__ pos) {
  int gid = blockIdx.x * 256 + threadIdx.x;   // BT_*H_*64 threads
  int d = gid & 63;
  int h = (gid >> 6) & 15;
  int bt = gid >> 10;
  const int* pi = (const int*)pos;
  long long pv = (pi[1] == 0 && pi[2] == 1) ? ((const long long*)pos)[bt]
                                            : (long long)pi[bt];
  float inv = exp2f((float)d * -0.2076205059304601f);  // 10000^(-d/64)
  float ang = (float)pv * inv;
  float s, c;
  sincosf(ang, &s, &c);
  size_t base = (size_t)bt * QKVLD_ + (size_t)h * HD_ + d;
  _Float16* q = qkv;
  _Float16* k = qkv + D_;
  float x1v = (float)q[base], x2v = (float)q[base + 64];
  q[base]      = (_Float16)(x1v * c - x2v * s);
  q[base + 64] = (_Float16)(x2v * c + x1v * s);
  x1v = (float)k[base]; x2v = (float)k[base + 64];
  k[base]      = (_Float16)(x1v * c - x2v * s);
  k[base + 64] = (_Float16)(x2v * c + x1v * s);
}

// ---------------- v[b][t][...] (ld stride) -> vt[(b*H+h)][d][t] -----------------
__global__ void vtrans_kernel(const _Float16* __restrict__ v, _Float16* __restrict__ vt,
                              int ld) {
  __shared__ _Float16 tile[32][33];
  int t0 = blockIdx.x * 32, d0 = blockIdx.y * 32, bh = blockIdx.z;
  int b = bh >> 4, h = bh & 15;
  int tx = threadIdx.x, ty = threadIdx.y;   // 32 x 8
  const _Float16* vb = v + (size_t)b * T_ * ld + (size_t)h * HD_;
#pragma unroll
  for (int r = 0; r < 32; r += 8)
    tile[ty + r][tx] = vb[(size_t)(t0 + ty + r) * ld + d0 + tx];
  __syncthreads();
  _Float16* vo = vt + ((size_t)bh * HD_ + d0) * T_ + t0;
#pragma unroll
  for (int r = 0; r < 32; r += 8)
    vo[(size_t)(ty + r) * T_ + tx] = tile[tx][ty + r];
}

// ---------------- causal softmax over one row of scores (in place) --------------
__global__ void softmax_kernel(_Float16* __restrict__ probs) {
  long long rowid = blockIdx.x;
  int i = (int)(rowid & (T_ - 1));
  _Float16* row = probs + (size_t)rowid * T_;
  int tid = threadIdx.x;
  int j0 = tid * 8;
  uint4 raw = *(const uint4*)(row + j0);
  const _Float16* ph = (const _Float16*)&raw;
  const float scale = 0.08838834764831845f;     // 1/sqrt(128)
  float vals[8];
  float mx = -1e30f;
#pragma unroll
  for (int l = 0; l < 8; l++) {
    float v = (j0 + l <= i) ? (float)ph[l] * scale : -1e30f;
    vals[l] = v; mx = fmaxf(mx, v);
  }
  __shared__ float red[256];
  red[tid] = mx; __syncthreads();
  for (int s = 128; s > 0; s >>= 1) { if (tid < s) red[tid] = fmaxf(red[tid], red[tid + s]); __syncthreads(); }
  float M = red[0]; __syncthreads();
  float se = 0.f;
#pragma unroll
  for (int l = 0; l < 8; l++) { float e = __expf(vals[l] - M); vals[l] = e; se += e; }
  red[tid] = se; __syncthreads();
  for (int s = 128; s > 0; s >>= 1) { if (tid < s) red[tid] += red[tid + s]; __syncthreads(); }
  float inv = 1.0f / red[0];
  _Float16 t[8] __attribute__((aligned(16)));
#pragma unroll
  for (int l = 0; l < 8; l++) t[l] = (j0 + l <= i) ? (_Float16)(vals[l] * inv) : (_Float16)0.f;
  *(uint4*)(row + j0) = *(const uint4*)t;
}

// ---------------- hu = silu(gate) * up  (written over gate) ---------------------
__global__ void silumul_kernel(_Float16* __restrict__ gate, const _Float16* __restrict__ up) {
  size_t idx = ((size_t)blockIdx.x * 256 + threadIdx.x) * 8;
  uint4 gr = *(const uint4*)(gate + idx);
  uint4 ur = *(const uint4*)(up + idx);
  const _Float16* gh = (const _Float16*)&gr;
  const _Float16* uh = (const _Float16*)&ur;
  _Float16 t[8] __attribute__((aligned(16)));
#pragma unroll
  for (int l = 0; l < 8; l++) {
    float x = (float)gh[l];
    float s = x / (1.0f + __expf(-x));
    t[l] = (_Float16)(s * (float)uh[l]);
  }
  *(uint4*)(gate + idx) = *(const uint4*)t;
}

// ================================================================================
extern "C" void kernel_launch(void* const* d_in, const int* in_sizes, int n_in,
                              void* d_out, int out_size, void* d_ws, size_t ws_size,
                              hipStream_t stream) {
  (void)in_sizes; (void)n_in; (void)out_size;
  const float* x   = (const float*)d_in[0];
  const void*  pos = d_in[1];
  const float* W[7] = { (const float*)d_in[2], (const float*)d_in[3],
                        (const float*)d_in[4], (const float*)d_in[5],
                        (const float*)d_in[6], (const float*)d_in[7],
                        (const float*)d_in[8] };              // q k v o g u d
  const float* g1  = (const float*)d_in[9];
  const float* g2  = (const float*)d_in[10];
  float* out = (float*)d_out;

  const int wk[7] = { D_, D_, D_, D_, D_, D_, FF_ };
  const int wn[7] = { D_, D_, D_, D_, FF_, FF_, D_ };

  char* p = (char*)d_ws;
  auto carve = [&](size_t bytes) { char* r = p; p += (bytes + 255) & ~(size_t)255; return r; };

  _Float16* probs = (_Float16*)carve((size_t)CH_ * T_ * T_ * 2);   // 64 MB; later: Wo parts, gate
  const size_t FLAT_NEED = (size_t)336 * 1024 * 1024;
  bool flat = ws_size >= FLAT_NEED;
  _Float16* w16[7];
  if (flat) {
    // q,k,v carved contiguously -> fused QKV weight matrix [6144][2048]
    for (int i = 0; i < 7; i++) w16[i] = (_Float16*)carve((size_t)wk[i] * wn[i] * 2);
  } else {
    _Float16* wslot = (_Float16*)carve((size_t)D_ * FF_ * 2);      // 32 MB slot
    w16[0] = wslot;
    w16[1] = wslot + (size_t)D_ * D_;
    w16[2] = wslot + (size_t)2 * D_ * D_;
    w16[3] = w16[4] = w16[5] = w16[6] = wslot;
  }
  _Float16* qkv = (_Float16*)carve((size_t)BT_ * QKVLD_ * 2);  // 48 MB
  _Float16* ob  = (_Float16*)carve((size_t)BT_ * D_ * 2);      // 16 MB (contig after qkv)
  _Float16* xn  = (_Float16*)carve((size_t)BT_ * D_ * 2);      // 16 MB; later: hb
  _Float16* vt  = (_Float16*)carve((size_t)BT_ * D_ * 2);      // 16 MB
  float*    x1  = (float*)   carve((size_t)BT_ * D_ * 4);      // 32 MB
  _Float16* gate = probs;        // 64 MB region, dead after PV
  _Float16* up   = qkv;          // spans qkv(48)+ob(16): both dead after Wo GEMM
  _Float16* hb   = xn;
  float* oparts = (float*)probs; // Wo split-K partials (2 x 32 MB); probs dead after PV
  float* dparts = (float*)qkv;   // Wd split-K partials (2 x 32 MB); up dead by then

  dim3 b328(32, 8);
  auto conv = [&](int i) {
    wconv_kernel<<<dim3(wn[i] / 32, wk[i] / 64), b328, 0, stream>>>(W[i], w16[i], wk[i], wn[i]);
  };
  if (flat) for (int i = 0; i < 7; i++) conv(i);

  // xn = rmsnorm(x, g1)
  rmsnorm_kernel<<<BT_, 256, 0, stream>>>(x, g1, xn);

  // fused qkv projection: [BT][6144] = xn @ [Wq;Wk;Wv]^T   (384 WGs)
  if (!flat) { conv(0); conv(1); conv(2); }
  gemm256<0><<<dim3(QKVLD_ / 256, BT_ / 256, 1), 512, 131072, stream>>>(
      xn, w16[0], qkv, nullptr, BT_, QKVLD_, D_, D_, D_, QKVLD_);

  // rope(q, k) in fused layout
  rope_kernel<<<(BT_ * H_ * 64) / 256, 256, 0, stream>>>(qkv, pos);

  // v transpose per head: vt[(b*H+h)][d][t]
  vtrans_kernel<<<dim3(T_ / 32, HD_ / 32, NP_), b328, 0, stream>>>(qkv + 2 * D_, vt, QKVLD_);

  // attention in chunks of CH_ (b,h) pairs (old 128x128 kernel: small K)
  for (int c = 0; c < NCH_; c++) {
    gemm_bt<1, 0, 2><<<dim3(T_ / 128, T_ / 128, CH_), 256, 0, stream>>>(
        qkv, qkv + D_, probs, nullptr, T_, T_, HD_, QKVLD_, QKVLD_, T_, c * CH_,
        (long long)T_ * QKVLD_, HD_, (long long)T_ * QKVLD_, HD_,
        (long long)T_ * T_, 0);
    softmax_kernel<<<CH_ * T_, 256, 0, stream>>>(probs);
    gemm_bt<2, 0, 1><<<dim3(1, T_ / 128, CH_), 256, 0, stream>>>(
        probs, vt, ob, nullptr, T_, HD_, T_, T_, T_, D_, c * CH_,
        (long long)T_ * T_, 0,
        16LL * HD_ * T_, (long long)HD_ * T_,
        (long long)T_ * D_, HD_);
  }

  // x1 = x + o @ Wo : split-K=2 partials (256 WGs, KP=1024 -> 16 tiles) + reduce
  if (!flat) conv(3);
  gemm256<2><<<dim3(D_ / 256, BT_ / 256, 2), 512, 131072, stream>>>(
      ob, w16[3], oparts, nullptr, BT_, D_, D_, D_, D_, D_);
  addred_kernel<<<(BT_ * D_ / 4) / 256, 256, 0, stream>>>(oparts, x, x1);

  // h = rmsnorm(x1, g2)
  rmsnorm_kernel<<<BT_, 256, 0, stream>>>(x1, g2, hb);

  // gate = h @ Wg ; up = h @ Wu   (512 WGs each)
  if (!flat) conv(4);
  gemm256<0><<<dim3(FF_ / 256, BT_ / 256, 1), 512, 131072, stream>>>(
      hb, w16[4], gate, nullptr, BT_, FF_, D_, D_, D_, FF_);
  if (!flat) conv(5);
  gemm256<0><<<dim3(FF_ / 256, BT_ / 256, 1), 512, 131072, stream>>>(
      hb, w16[5], up, nullptr, BT_, FF_, D_, D_, D_, FF_);

  // hu = silu(gate) * up  (in gate)
  silumul_kernel<<<(BT_ * FF_ / 8) / 256, 256, 0, stream>>>(gate, up);

  // Wd split-K=2: partials = hu @ Wd (per half-K, KP=4096 -> 64 tiles), then reduce
  if (!flat) conv(6);
  gemm256<2><<<dim3(D_ / 256, BT_ / 256, 2), 512, 131072, stream>>>(
      gate, w16[6], dparts, nullptr, BT_, D_, FF_, FF_, FF_, D_);
  addred_kernel<<<(BT_ * D_ / 4) / 256, 256, 0, stream>>>(dparts, x1, out);
}

// Round 7
// 1267.766 us; speedup vs baseline: 1.0464x; 1.0198x over previous
//
#include <hip/hip_runtime.h>
#include <cstdint>

#define D_  2048
#define H_  16
#define HD_ 128
#define FF_ 8192
#define T_  2048
#define B_  2
#define BT_ (B_*T_)
#define NP_ (B_*H_)        // 32 (b,h) pairs
#define CH_ 8              // pairs per attention chunk
#define NCH_ (NP_/CH_)     // 4 chunks
#define QKVLD_ (3*D_)      // fused qkv row stride (6144)

typedef __attribute__((ext_vector_type(8))) _Float16 half8;
typedef __attribute__((ext_vector_type(4))) float   floatx4;

// async global->LDS, 16B per lane; LDS dest = wave-uniform base + lane*16
__device__ __forceinline__ void gl_lds16(const void* g, void* l) {
  __builtin_amdgcn_global_load_lds(
      (const __attribute__((address_space(1))) void*)(uintptr_t)g,
      (__attribute__((address_space(3))) void*)(uintptr_t)l,
      16, 0, 0);
}

// ---------------- weight convert + transpose: W[K][N] f32 -> Wt[N][K] f16 ----
__global__ void wconv_kernel(const float* __restrict__ W, _Float16* __restrict__ Wt,
                             int K, int N) {
  __shared__ float tile[64][33];
  int n0 = blockIdx.x * 32, k0 = blockIdx.y * 64;
  int tx = threadIdx.x, ty = threadIdx.y;   // 32 x 8
#pragma unroll
  for (int r = 0; r < 64; r += 8)
    tile[ty + r][tx] = W[(size_t)(k0 + ty + r) * N + n0 + tx];
  __syncthreads();
#pragma unroll
  for (int r = 0; r < 32; r += 8) {
    float a = tile[tx * 2][ty + r], b = tile[tx * 2 + 1][ty + r];
    union { _Float16 h[2]; unsigned u; } cv;
    cv.h[0] = (_Float16)a; cv.h[1] = (_Float16)b;
    ((unsigned*)(Wt + (size_t)(n0 + ty + r) * K + k0))[tx] = cv.u;
  }
}

// ---------------- rmsnorm: fp32 row -> fp16 row --------------------------------
__global__ void rmsnorm_kernel(const float* __restrict__ x, const float* __restrict__ g,
                               _Float16* __restrict__ out) {
  int row = blockIdx.x, tid = threadIdx.x;
  const float4* xr = (const float4*)(x + (size_t)row * D_);
  float4 v1 = xr[tid], v2 = xr[tid + 256];
  float ss = v1.x*v1.x + v1.y*v1.y + v1.z*v1.z + v1.w*v1.w
           + v2.x*v2.x + v2.y*v2.y + v2.z*v2.z + v2.w*v2.w;
  __shared__ float red[256];
  red[tid] = ss; __syncthreads();
  for (int s = 128; s > 0; s >>= 1) { if (tid < s) red[tid] += red[tid + s]; __syncthreads(); }
  float rs = rsqrtf(red[0] * (1.0f / D_) + 1e-6f);
  float4 ga = ((const float4*)g)[tid], gb = ((const float4*)g)[tid + 256];
  _Float16* orow = out + (size_t)row * D_;
  _Float16 t[4] __attribute__((aligned(8)));
  t[0] = (_Float16)(v1.x * rs * ga.x);
  t[1] = (_Float16)(v1.y * rs * ga.y);
  t[2] = (_Float16)(v1.z * rs * ga.z);
  t[3] = (_Float16)(v1.w * rs * ga.w);
  *(uint2*)(orow + tid * 4) = *(const uint2*)t;
  t[0] = (_Float16)(v2.x * rs * gb.x);
  t[1] = (_Float16)(v2.y * rs * gb.y);
  t[2] = (_Float16)(v2.z * rs * gb.z);
  t[3] = (_Float16)(v2.w * rs * gb.w);
  *(uint2*)(orow + (tid + 256) * 4) = *(const uint2*)t;
}

// ================================================================================
// 8-phase GEMM (m201 schedule), C = A @ Bt^T. 256x256 tile, BK=64, 8 waves
// (2Mx4N), wave tile 128x64. LDS (bytes): [slot0: A 32K | B 32K][slot1: A|B]
// = 128 KiB double buffer. K-loop UNROLLED 2 tiles/iter -> slot indices are
// literals; all ds_read addresses are {8 precomputed per-lane base VGPRs}
// + compile-time imm (max 46KB < 65535); stage addresses are 2 advancing
// global pointers + static offsets. Zero per-phase address VALU.
// Phase shape: {ds-reads | stage 1 half-tile | [lgkm(8) if 12 reads] | barrier
// | lgkmcnt(0)+sched_barrier | setprio1 | 16 MFMA | setprio0 | barrier};
// vmcnt(4) once per K-tile at Ph4 (2 stage-pairs in flight, never 0 mid-loop).
// Stage plan: Ph1/Ph2(t): A halves of t+1 (slot^1; A(t-1) last read Ph4(t-1),
// drained+barriered). Ph3/Ph4(t): B halves of t+2 (slot; B(t) read only in
// Ph1(t), drained+barriered). RAW: end-Ph4(t) vmcnt(4) retires through
// A1(t+1) -> tile t+1 fully landed before Ph1(t+1). Swizzle: phys 16B chunk =
// logical ^ (row&7) on pre-swizzled global source + ds_read addr (0-conflict).
// OUTMODE: 0 -> C f16 = acc; 1 -> C f32 = acc + Res; 2 -> C f32 partial at bz.
// Requires M%256==0, N%256==0, (K/gz)%128==0 (NT even), total WGs %8==0.
template<int OUTMODE>
__global__ __launch_bounds__(512, 2) void gemm256(
    const _Float16* __restrict__ A, const _Float16* __restrict__ Bt,
    void* __restrict__ Cv, const float* __restrict__ Res,
    int M, int N, int K, int lda, int ldb, int ldc)
{
  extern __shared__ _Float16 smem[];   // [2][A:16384 | B:16384] elems

  // XCD-bijective remap
  const int gx = gridDim.x, gy = gridDim.y, gz = gridDim.z;
  int pid = (blockIdx.z * gy + blockIdx.y) * gx + blockIdx.x;
  const int qch = (gx * gy * gz) >> 3;
  int lid = (pid & 7) * qch + (pid >> 3);
  const int bx = lid % gx; lid /= gx;
  const int by = lid % gy; const int bz = lid / gy;

  const int tid  = threadIdx.x;
  const int lane = tid & 63;
  const int w    = tid >> 6;          // 0..7
  const int wm   = w >> 2;            // 0..1
  const int wn   = w & 3;             // 0..3
  const int l15  = lane & 15, q4 = lane >> 4;
  const int m0   = by * 256;
  const int n0   = bx * 256;
  const int KP   = K / gz;
  const int koff = bz * KP;
  const int NT   = KP >> 6;           // K-tiles of 64 (even)

  // staging: lane L covers row (w*8 + L>>3), phys chunk (L&7); global column
  // pre-swizzled so LDS phys chunk p of row r holds logical chunk p^(r&7).
  const int srow8  = lane >> 3;
  const int schunk = (((lane & 7) ^ (srow8 & 7)) << 3);
  const _Float16* AgP = A  + (size_t)(m0 + w * 8 + srow8) * lda + schunk + koff;
  const _Float16* BgP = Bt + (size_t)(n0 + w * 8 + srow8) * ldb + schunk + koff;
  const int ldsW = w * 512;

  // read bases: logical chunk c at row r lives at phys c^(r&7); r&7 == l15&7.
  const int c0 = ((q4 ^ (l15 & 7)) << 3);
  const int c1 = c0 ^ 32;
  const int arow_e = (wm * 128 + l15) * 64;
  const int brow_e = (wn * 64 + l15) * 64;
  const _Float16* aB[2][2];   // [slot][kk] — literal-indexed only
  const _Float16* bB[2][2];
  aB[0][0] = smem + arow_e + c0;          aB[0][1] = smem + arow_e + c1;
  aB[1][0] = aB[0][0] + 32768;            aB[1][1] = aB[0][1] + 32768;
  bB[0][0] = smem + 16384 + brow_e + c0;  bB[0][1] = smem + 16384 + brow_e + c1;
  bB[1][0] = bB[0][0] + 32768;            bB[1][1] = bB[0][1] + 32768;

  floatx4 acc[8][4];
#pragma unroll
  for (int i = 0; i < 8; ++i)
#pragma unroll
    for (int j = 0; j < 4; ++j)
#pragma unroll
      for (int r = 0; r < 4; ++r) acc[i][j][r] = 0.0f;

  half8 bf[2][4];
  half8 af0[4], af1[4];

  // stage: S = dest slot (literal), h/s = half/seg (literals), KO = elem offset
  // from the advancing pointer (literal: tiles ahead * 64).
#define STA(S, h, s, KO)                                                     \
  gl_lds16(AgP + (size_t)((h) * 128 + (s) * 64) * lda + (KO),                \
           smem + (S) * 32768 + (h) * 8192 + (s) * 4096 + ldsW)
#define STB(S, h, s, KO)                                                     \
  gl_lds16(BgP + (size_t)((h) * 128 + (s) * 64) * ldb + (KO),                \
           smem + (S) * 32768 + 16384 + (h) * 8192 + (s) * 4096 + ldsW)

#define SB0   __builtin_amdgcn_sched_barrier(0)
#define BARR  __builtin_amdgcn_s_barrier()
#define LGKM0 asm volatile("s_waitcnt lgkmcnt(0)" ::: "memory")

#define RD_B8(S)                                                             \
  { _Pragma("unroll")                                                        \
    for (int j = 0; j < 4; ++j) {                                            \
      bf[0][j] = *(const half8*)(bB[S][0] + j * 1024);                       \
      bf[1][j] = *(const half8*)(bB[S][1] + j * 1024);                       \
    } }
#define RD_A4(S, q, af)                                                      \
  { _Pragma("unroll")                                                        \
    for (int i2 = 0; i2 < 2; ++i2) {                                         \
      af[i2*2+0] = *(const half8*)(aB[S][0] + ((q)*2+i2) * 1024);            \
      af[i2*2+1] = *(const half8*)(aB[S][1] + ((q)*2+i2) * 1024);            \
    } }
#define MFMA_Q(q, af)                                                        \
  { _Pragma("unroll")                                                        \
    for (int kk = 0; kk < 2; ++kk)                                           \
      _Pragma("unroll")                                                      \
      for (int i2 = 0; i2 < 2; ++i2)                                         \
        _Pragma("unroll")                                                    \
        for (int j = 0; j < 4; ++j)                                          \
          acc[(q)*2+i2][j] = __builtin_amdgcn_mfma_f32_16x16x32_f16(         \
              af[i2*2+kk], bf[kk][j], acc[(q)*2+i2][j], 0, 0, 0);            \
  }

  // One K-tile: S = its slot (literal); KOA/KOB = stage offsets (literals):
  // A stages target tile t+1 (KOA), B stages target tile t+2 (KOB).
#define TILE(S, t, KOA, KOB)                                                 \
  {                                                                          \
    const bool s1 = (t) + 1 < NT, s2 = (t) + 2 < NT;                         \
    /* Ph1: all B + A-quad0 */                                               \
    RD_B8(S); RD_A4(S, 0, af0);                                              \
    if (s1) { STA((S) ^ 1, 0, 0, KOA); STA((S) ^ 1, 0, 1, KOA); }            \
    asm volatile("s_waitcnt lgkmcnt(8)" ::: "memory");                       \
    SB0; BARR; LGKM0; SB0;                                                   \
    __builtin_amdgcn_s_setprio(1); MFMA_Q(0, af0); __builtin_amdgcn_s_setprio(0); \
    SB0; BARR;                                                               \
    /* Ph2: A-quad1 */                                                       \
    RD_A4(S, 1, af1);                                                        \
    if (s1) { STA((S) ^ 1, 1, 0, KOA); STA((S) ^ 1, 1, 1, KOA); }            \
    SB0; BARR; LGKM0; SB0;                                                   \
    __builtin_amdgcn_s_setprio(1); MFMA_Q(1, af1); __builtin_amdgcn_s_setprio(0); \
    SB0; BARR;                                                               \
    /* Ph3: A-quad2 */                                                       \
    RD_A4(S, 2, af0);                                                        \
    if (s2) { STB(S, 0, 0, KOB); STB(S, 0, 1, KOB); }                        \
    SB0; BARR; LGKM0; SB0;                                                   \
    __builtin_amdgcn_s_setprio(1); MFMA_Q(2, af0); __builtin_amdgcn_s_setprio(0); \
    SB0; BARR;                                                               \
    /* Ph4: A-quad3 */                                                       \
    RD_A4(S, 3, af1);                                                        \
    if (s2) { STB(S, 1, 0, KOB); STB(S, 1, 1, KOB); }                        \
    SB0; BARR; LGKM0; SB0;                                                   \
    __builtin_amdgcn_s_setprio(1); MFMA_Q(3, af1); __builtin_amdgcn_s_setprio(0); \
    SB0;                                                                     \
    if (s2)      asm volatile("s_waitcnt vmcnt(4)" ::: "memory");            \
    else if (s1) asm volatile("s_waitcnt vmcnt(0)" ::: "memory");            \
    BARR;                                                                    \
  }

  // prologue: tile0 fully + B halves of tile1; vmcnt(4) -> tile0 landed,
  // B(1) (4 loads) in flight — matches steady-state entry at Ph1(0).
  STA(0, 0, 0, 0); STA(0, 0, 1, 0); STA(0, 1, 0, 0); STA(0, 1, 1, 0);
  STB(0, 0, 0, 0); STB(0, 0, 1, 0); STB(0, 1, 0, 0); STB(0, 1, 1, 0);
  if (NT > 1) {
    STB(1, 0, 0, 64); STB(1, 0, 1, 64); STB(1, 1, 0, 64); STB(1, 1, 1, 64);
    asm volatile("s_waitcnt vmcnt(4)" ::: "memory");
  } else {
    asm volatile("s_waitcnt vmcnt(0)" ::: "memory");
  }
  BARR;

  for (int t = 0; t < NT; t += 2) {
    TILE(0, t,     64, 128);
    TILE(1, t + 1, 128, 192);
    AgP += 128; BgP += 128;
  }

#undef STA
#undef STB
#undef SB0
#undef BARR
#undef LGKM0
#undef RD_B8
#undef RD_A4
#undef MFMA_Q
#undef TILE

  // epilogue: C/D layout col=lane&15, row=(lane>>4)*4+r
  const int crow0 = m0 + wm * 128 + q4 * 4;
  const int ccol0 = n0 + wn * 64 + l15;
#pragma unroll
  for (int i = 0; i < 8; ++i)
#pragma unroll
    for (int j = 0; j < 4; ++j)
#pragma unroll
      for (int r = 0; r < 4; ++r) {
        size_t o = (size_t)(crow0 + i * 16 + r) * ldc + (ccol0 + j * 16);
        if constexpr (OUTMODE == 0)      ((_Float16*)Cv)[o] = (_Float16)acc[i][j][r];
        else if constexpr (OUTMODE == 1) ((float*)Cv)[o] = acc[i][j][r] + Res[o];
        else ((float*)Cv)[(size_t)bz * M * ldc + o] = acc[i][j][r];
      }
}

// ---------------- split-K reduce: out = p0 + p1 + res (all f32) -----------------
__global__ void addred_kernel(const float* __restrict__ parts, const float* __restrict__ res,
                              float* __restrict__ out) {
  size_t i = ((size_t)blockIdx.x * 256 + threadIdx.x) * 4;
  const size_t MN = (size_t)BT_ * D_;
  float4 a = *(const float4*)(parts + i);
  float4 b = *(const float4*)(parts + MN + i);
  float4 r = *(const float4*)(res + i);
  float4 o;
  o.x = a.x + b.x + r.x; o.y = a.y + b.y + r.y;
  o.z = a.z + b.z + r.z; o.w = a.w + b.w + r.w;
  *(float4*)(out + i) = o;
}

// ---------------- old 128x128 MFMA GEMM (attention scores / PV only) ------------
template<int CMODE, int ADDRES, int LOCALS>
__global__ __launch_bounds__(256, 3) void gemm_bt(
    const _Float16* __restrict__ A, const _Float16* __restrict__ Bt,
    void* __restrict__ Cv, const float* __restrict__ Res,
    int M, int N, int K, int lda, int ldb, int ldc, int pair0,
    long long sAd, long long sAm, long long sBd, long long sBm,
    long long sCd, long long sCm)
{
  const int gx = gridDim.x, gy = gridDim.y;
  int pid = (blockIdx.z * gy + blockIdx.y) * gx + blockIdx.x;
  const int qch = (gx * gy * gridDim.z) >> 3;
  int lid = (pid & 7) * qch + (pid >> 3);
  const int bxx = lid % gx; lid /= gx;
  const int byy = lid % gy; const int bzz = lid / gy;

  int zl = bzz;
  int p = pair0 + zl;
  long long aoff = (LOCALS & 1) ? (long long)zl * sAd
                                : (long long)(p >> 4) * sAd + (long long)(p & 15) * sAm;
  long long boff = (long long)(p >> 4) * sBd + (long long)(p & 15) * sBm;
  long long coff = (LOCALS & 2) ? (long long)zl * sCd
                                : (long long)(p >> 4) * sCd + (long long)(p & 15) * sCm;
  const _Float16* Ab = A + (size_t)aoff;
  const _Float16* Bb = Bt + (size_t)boff;
  int m0 = byy * 128, n0 = bxx * 128;
  if (CMODE == 1 && n0 > m0 + 127) return;
  int kmax = K;
  if (CMODE == 2) kmax = min(K, m0 + 128);

  __shared__ __align__(16) _Float16 As[128 * 32];
  __shared__ __align__(16) _Float16 Bs[128 * 32];

  int tid = threadIdx.x;
  int lane = tid & 63;
  int w = tid >> 6;
  int wm = ((tid >> 7) & 1) * 64;
  int wn = ((tid >> 6) & 1) * 64;
  int l15 = lane & 15, q4 = lane >> 4;

  int arow = w * 32;
  int lrow = lane >> 2, lcol = (lane & 3) * 8;
  const _Float16* Ag = Ab + (size_t)(m0 + arow + lrow) * lda + lcol;
  const _Float16* Bg = Bb + (size_t)(n0 + arow + lrow) * ldb + lcol;
  const _Float16* Ag2 = Ag + (size_t)16 * lda;
  const _Float16* Bg2 = Bg + (size_t)16 * ldb;
  _Float16* lA  = &As[arow * 32];
  _Float16* lA2 = &As[(arow + 16) * 32];
  _Float16* lB  = &Bs[arow * 32];
  _Float16* lB2 = &Bs[(arow + 16) * 32];

  floatx4 acc[4][4];
#pragma unroll
  for (int i = 0; i < 4; i++)
#pragma unroll
    for (int j = 0; j < 4; j++)
#pragma unroll
      for (int r = 0; r < 4; r++) acc[i][j][r] = 0.0f;

  for (int k0 = 0; k0 < kmax; k0 += 32) {
    gl_lds16(Ag + k0, lA);
    gl_lds16(Ag2 + k0, lA2);
    gl_lds16(Bg + k0, lB);
    gl_lds16(Bg2 + k0, lB2);
    __syncthreads();
    half8 af[4], bfr[4];
#pragma unroll
    for (int i = 0; i < 4; i++)
      af[i] = *(const half8*)(&As[(wm + i * 16 + l15) * 32 + q4 * 8]);
#pragma unroll
    for (int j = 0; j < 4; j++)
      bfr[j] = *(const half8*)(&Bs[(wn + j * 16 + l15) * 32 + q4 * 8]);
#pragma unroll
    for (int i = 0; i < 4; i++)
#pragma unroll
      for (int j = 0; j < 4; j++)
        acc[i][j] = __builtin_amdgcn_mfma_f32_16x16x32_f16(af[i], bfr[j], acc[i][j], 0, 0, 0);
    __syncthreads();
  }

#pragma unroll
  for (int i = 0; i < 4; i++) {
#pragma unroll
    for (int j = 0; j < 4; j++) {
#pragma unroll
      for (int r = 0; r < 4; r++) {
        int row = m0 + wm + i * 16 + q4 * 4 + r;
        int col = n0 + wn + j * 16 + l15;
        size_t o = (size_t)(coff + (long long)row * ldc + col);
        if (ADDRES) ((float*)Cv)[o] = acc[i][j][r] + Res[o];
        else        ((_Float16*)Cv)[o] = (_Float16)acc[i][j][r];
      }
    }
  }
}

// ---------------- RoPE on fused qkv (q at col 0, k at col D_) -------------------
__global__ void rope_kernel(_Float16* __restrict__ qkv, const void* __restrict__ pos) {
  int gid = blockIdx.x * 256 + threadIdx.x;   // BT_*H_*64 threads
  int d = gid & 63;
  int h = (gid >> 6) & 15;
  int bt = gid >> 10;
  const int* pi = (const int*)pos;
  long long pv = (pi[1] == 0 && pi[2] == 1) ? ((const long long*)pos)[bt]
                                            : (long long)pi[bt];
  float inv = exp2f((float)d * -0.2076205059304601f);  // 10000^(-d/64)
  float ang = (float)pv * inv;
  float s, c;
  sincosf(ang, &s, &c);
  size_t base = (size_t)bt * QKVLD_ + (size_t)h * HD_ + d;
  _Float16* q = qkv;
  _Float16* k = qkv + D_;
  float x1v = (float)q[base], x2v = (float)q[base + 64];
  q[base]      = (_Float16)(x1v * c - x2v * s);
  q[base + 64] = (_Float16)(x2v * c + x1v * s);
  x1v = (float)k[base]; x2v = (float)k[base + 64];
  k[base]      = (_Float16)(x1v * c - x2v * s);
  k[base + 64] = (_Float16)(x2v * c + x1v * s);
}

// ---------------- v[b][t][...] (ld stride) -> vt[(b*H+h)][d][t] -----------------
__global__ void vtrans_kernel(const _Float16* __restrict__ v, _Float16* __restrict__ vt,
                              int ld) {
  __shared__ _Float16 tile[32][33];
  int t0 = blockIdx.x * 32, d0 = blockIdx.y * 32, bh = blockIdx.z;
  int b = bh >> 4, h = bh & 15;
  int tx = threadIdx.x, ty = threadIdx.y;   // 32 x 8
  const _Float16* vb = v + (size_t)b * T_ * ld + (size_t)h * HD_;
#pragma unroll
  for (int r = 0; r < 32; r += 8)
    tile[ty + r][tx] = vb[(size_t)(t0 + ty + r) * ld + d0 + tx];
  __syncthreads();
  _Float16* vo = vt + ((size_t)bh * HD_ + d0) * T_ + t0;
#pragma unroll
  for (int r = 0; r < 32; r += 8)
    vo[(size_t)(ty + r) * T_ + tx] = tile[tx][ty + r];
}

// ---------------- causal softmax over one row of scores (in place) --------------
__global__ void softmax_kernel(_Float16* __restrict__ probs) {
  long long rowid = blockIdx.x;
  int i = (int)(rowid & (T_ - 1));
  _Float16* row = probs + (size_t)rowid * T_;
  int tid = threadIdx.x;
  int j0 = tid * 8;
  uint4 raw = *(const uint4*)(row + j0);
  const _Float16* ph = (const _Float16*)&raw;
  const float scale = 0.08838834764831845f;     // 1/sqrt(128)
  float vals[8];
  float mx = -1e30f;
#pragma unroll
  for (int l = 0; l < 8; l++) {
    float v = (j0 + l <= i) ? (float)ph[l] * scale : -1e30f;
    vals[l] = v; mx = fmaxf(mx, v);
  }
  __shared__ float red[256];
  red[tid] = mx; __syncthreads();
  for (int s = 128; s > 0; s >>= 1) { if (tid < s) red[tid] = fmaxf(red[tid], red[tid + s]); __syncthreads(); }
  float M = red[0]; __syncthreads();
  float se = 0.f;
#pragma unroll
  for (int l = 0; l < 8; l++) { float e = __expf(vals[l] - M); vals[l] = e; se += e; }
  red[tid] = se; __syncthreads();
  for (int s = 128; s > 0; s >>= 1) { if (tid < s) red[tid] += red[tid + s]; __syncthreads(); }
  float inv = 1.0f / red[0];
  _Float16 t[8] __attribute__((aligned(16)));
#pragma unroll
  for (int l = 0; l < 8; l++) t[l] = (j0 + l <= i) ? (_Float16)(vals[l] * inv) : (_Float16)0.f;
  *(uint4*)(row + j0) = *(const uint4*)t;
}

// ---------------- hu = silu(gate) * up  (written over gate) ---------------------
__global__ void silumul_kernel(_Float16* __restrict__ gate, const _Float16* __restrict__ up) {
  size_t idx = ((size_t)blockIdx.x * 256 + threadIdx.x) * 8;
  uint4 gr = *(const uint4*)(gate + idx);
  uint4 ur = *(const uint4*)(up + idx);
  const _Float16* gh = (const _Float16*)&gr;
  const _Float16* uh = (const _Float16*)&ur;
  _Float16 t[8] __attribute__((aligned(16)));
#pragma unroll
  for (int l = 0; l < 8; l++) {
    float x = (float)gh[l];
    float s = x / (1.0f + __expf(-x));
    t[l] = (_Float16)(s * (float)uh[l]);
  }
  *(uint4*)(gate + idx) = *(const uint4*)t;
}

// ================================================================================
extern "C" void kernel_launch(void* const* d_in, const int* in_sizes, int n_in,
                              void* d_out, int out_size, void* d_ws, size_t ws_size,
                              hipStream_t stream) {
  (void)in_sizes; (void)n_in; (void)out_size;
  const float* x   = (const float*)d_in[0];
  const void*  pos = d_in[1];
  const float* W[7] = { (const float*)d_in[2], (const float*)d_in[3],
                        (const float*)d_in[4], (const float*)d_in[5],
                        (const float*)d_in[6], (const float*)d_in[7],
                        (const float*)d_in[8] };              // q k v o g u d
  const float* g1  = (const float*)d_in[9];
  const float* g2  = (const float*)d_in[10];
  float* out = (float*)d_out;

  const int wk[7] = { D_, D_, D_, D_, D_, D_, FF_ };
  const int wn[7] = { D_, D_, D_, D_, FF_, FF_, D_ };

  char* p = (char*)d_ws;
  auto carve = [&](size_t bytes) { char* r = p; p += (bytes + 255) & ~(size_t)255; return r; };

  _Float16* probs = (_Float16*)carve((size_t)CH_ * T_ * T_ * 2);   // 64 MB; later: Wo parts, gate
  const size_t FLAT_NEED = (size_t)336 * 1024 * 1024;
  bool flat = ws_size >= FLAT_NEED;
  _Float16* w16[7];
  if (flat) {
    // q,k,v carved contiguously -> fused QKV weight matrix [6144][2048]
    for (int i = 0; i < 7; i++) w16[i] = (_Float16*)carve((size_t)wk[i] * wn[i] * 2);
  } else {
    _Float16* wslot = (_Float16*)carve((size_t)D_ * FF_ * 2);      // 32 MB slot
    w16[0] = wslot;
    w16[1] = wslot + (size_t)D_ * D_;
    w16[2] = wslot + (size_t)2 * D_ * D_;
    w16[3] = w16[4] = w16[5] = w16[6] = wslot;
  }
  _Float16* qkv = (_Float16*)carve((size_t)BT_ * QKVLD_ * 2);  // 48 MB
  _Float16* ob  = (_Float16*)carve((size_t)BT_ * D_ * 2);      // 16 MB (contig after qkv)
  _Float16* xn  = (_Float16*)carve((size_t)BT_ * D_ * 2);      // 16 MB; later: hb
  _Float16* vt  = (_Float16*)carve((size_t)BT_ * D_ * 2);      // 16 MB
  float*    x1  = (float*)   carve((size_t)BT_ * D_ * 4);      // 32 MB
  _Float16* gate = probs;        // 64 MB region, dead after PV
  _Float16* up   = qkv;          // spans qkv(48)+ob(16): both dead after Wo GEMM
  _Float16* hb   = xn;
  float* oparts = (float*)probs; // Wo split-K partials (2 x 32 MB); probs dead after PV
  float* dparts = (float*)qkv;   // Wd split-K partials (2 x 32 MB); up dead by then

  dim3 b328(32, 8);
  auto conv = [&](int i) {
    wconv_kernel<<<dim3(wn[i] / 32, wk[i] / 64), b328, 0, stream>>>(W[i], w16[i], wk[i], wn[i]);
  };
  if (flat) for (int i = 0; i < 7; i++) conv(i);

  // xn = rmsnorm(x, g1)
  rmsnorm_kernel<<<BT_, 256, 0, stream>>>(x, g1, xn);

  // fused qkv projection: [BT][6144] = xn @ [Wq;Wk;Wv]^T   (384 WGs)
  if (!flat) { conv(0); conv(1); conv(2); }
  gemm256<0><<<dim3(QKVLD_ / 256, BT_ / 256, 1), 512, 131072, stream>>>(
      xn, w16[0], qkv, nullptr, BT_, QKVLD_, D_, D_, D_, QKVLD_);

  // rope(q, k) in fused layout
  rope_kernel<<<(BT_ * H_ * 64) / 256, 256, 0, stream>>>(qkv, pos);

  // v transpose per head: vt[(b*H+h)][d][t]
  vtrans_kernel<<<dim3(T_ / 32, HD_ / 32, NP_), b328, 0, stream>>>(qkv + 2 * D_, vt, QKVLD_);

  // attention in chunks of CH_ (b,h) pairs (old 128x128 kernel: small K)
  for (int c = 0; c < NCH_; c++) {
    gemm_bt<1, 0, 2><<<dim3(T_ / 128, T_ / 128, CH_), 256, 0, stream>>>(
        qkv, qkv + D_, probs, nullptr, T_, T_, HD_, QKVLD_, QKVLD_, T_, c * CH_,
        (long long)T_ * QKVLD_, HD_, (long long)T_ * QKVLD_, HD_,
        (long long)T_ * T_, 0);
    softmax_kernel<<<CH_ * T_, 256, 0, stream>>>(probs);
    gemm_bt<2, 0, 1><<<dim3(1, T_ / 128, CH_), 256, 0, stream>>>(
        probs, vt, ob, nullptr, T_, HD_, T_, T_, T_, D_, c * CH_,
        (long long)T_ * T_, 0,
        16LL * HD_ * T_, (long long)HD_ * T_,
        (long long)T_ * D_, HD_);
  }

  // x1 = x + o @ Wo : split-K=2 partials (256 WGs, KP=1024 -> 16 tiles) + reduce
  if (!flat) conv(3);
  gemm256<2><<<dim3(D_ / 256, BT_ / 256, 2), 512, 131072, stream>>>(
      ob, w16[3], oparts, nullptr, BT_, D_, D_, D_, D_, D_);
  addred_kernel<<<(BT_ * D_ / 4) / 256, 256, 0, stream>>>(oparts, x, x1);

  // h = rmsnorm(x1, g2)
  rmsnorm_kernel<<<BT_, 256, 0, stream>>>(x1, g2, hb);

  // gate = h @ Wg ; up = h @ Wu   (512 WGs each)
  if (!flat) conv(4);
  gemm256<0><<<dim3(FF_ / 256, BT_ / 256, 1), 512, 131072, stream>>>(
      hb, w16[4], gate, nullptr, BT_, FF_, D_, D_, D_, FF_);
  if (!flat) conv(5);
  gemm256<0><<<dim3(FF_ / 256, BT_ / 256, 1), 512, 131072, stream>>>(
      hb, w16[5], up, nullptr, BT_, FF_, D_, D_, D_, FF_);

  // hu = silu(gate) * up  (in gate)
  silumul_kernel<<<(BT_ * FF_ / 8) / 256, 256, 0, stream>>>(gate, up);

  // Wd split-K=2: partials = hu @ Wd (per half-K, KP=4096 -> 64 tiles), then reduce
  if (!flat) conv(6);
  gemm256<2><<<dim3(D_ / 256, BT_ / 256, 2), 512, 131072, stream>>>(
      gate, w16[6], dparts, nullptr, BT_, D_, FF_, FF_, FF_, D_);
  addred_kernel<<<(BT_ * D_ / 4) / 256, 256, 0, stream>>>(dparts, x1, out);
}

// Round 8
// 1178.656 us; speedup vs baseline: 1.1255x; 1.0756x over previous
//
#include <hip/hip_runtime.h>
#include <cstdint>

#define D_  2048
#define H_  16
#define HD_ 128
#define FF_ 8192
#define T_  2048
#define B_  2
#define BT_ (B_*T_)
#define NP_ (B_*H_)        // 32 (b,h) pairs
#define QKVLD_ (3*D_)      // fused qkv row stride (6144)

typedef __attribute__((ext_vector_type(8))) _Float16 half8;
typedef __attribute__((ext_vector_type(4))) float   floatx4;

// async global->LDS, 16B per lane; LDS dest = wave-uniform base + lane*16
__device__ __forceinline__ void gl_lds16(const void* g, void* l) {
  __builtin_amdgcn_global_load_lds(
      (const __attribute__((address_space(1))) void*)(uintptr_t)g,
      (__attribute__((address_space(3))) void*)(uintptr_t)l,
      16, 0, 0);
}

// ---------------- weight convert + transpose: W[K][N] f32 -> Wt[N][K] f16 ----
__global__ void wconv_kernel(const float* __restrict__ W, _Float16* __restrict__ Wt,
                             int K, int N) {
  __shared__ float tile[64][33];
  int n0 = blockIdx.x * 32, k0 = blockIdx.y * 64;
  int tx = threadIdx.x, ty = threadIdx.y;   // 32 x 8
#pragma unroll
  for (int r = 0; r < 64; r += 8)
    tile[ty + r][tx] = W[(size_t)(k0 + ty + r) * N + n0 + tx];
  __syncthreads();
#pragma unroll
  for (int r = 0; r < 32; r += 8) {
    float a = tile[tx * 2][ty + r], b = tile[tx * 2 + 1][ty + r];
    union { _Float16 h[2]; unsigned u; } cv;
    cv.h[0] = (_Float16)a; cv.h[1] = (_Float16)b;
    ((unsigned*)(Wt + (size_t)(n0 + ty + r) * K + k0))[tx] = cv.u;
  }
}

// ---------------- rmsnorm: fp32 row -> fp16 row --------------------------------
__global__ void rmsnorm_kernel(const float* __restrict__ x, const float* __restrict__ g,
                               _Float16* __restrict__ out) {
  int row = blockIdx.x, tid = threadIdx.x;
  const float4* xr = (const float4*)(x + (size_t)row * D_);
  float4 v1 = xr[tid], v2 = xr[tid + 256];
  float ss = v1.x*v1.x + v1.y*v1.y + v1.z*v1.z + v1.w*v1.w
           + v2.x*v2.x + v2.y*v2.y + v2.z*v2.z + v2.w*v2.w;
  __shared__ float red[256];
  red[tid] = ss; __syncthreads();
  for (int s = 128; s > 0; s >>= 1) { if (tid < s) red[tid] += red[tid + s]; __syncthreads(); }
  float rs = rsqrtf(red[0] * (1.0f / D_) + 1e-6f);
  float4 ga = ((const float4*)g)[tid], gb = ((const float4*)g)[tid + 256];
  _Float16* orow = out + (size_t)row * D_;
  _Float16 t[4] __attribute__((aligned(8)));
  t[0] = (_Float16)(v1.x * rs * ga.x);
  t[1] = (_Float16)(v1.y * rs * ga.y);
  t[2] = (_Float16)(v1.z * rs * ga.z);
  t[3] = (_Float16)(v1.w * rs * ga.w);
  *(uint2*)(orow + tid * 4) = *(const uint2*)t;
  t[0] = (_Float16)(v2.x * rs * gb.x);
  t[1] = (_Float16)(v2.y * rs * gb.y);
  t[2] = (_Float16)(v2.z * rs * gb.z);
  t[3] = (_Float16)(v2.w * rs * gb.w);
  *(uint2*)(orow + (tid + 256) * 4) = *(const uint2*)t;
}

// ================================================================================
// 8-phase GEMM (m201 schedule), C = A @ Bt^T. 256x256 tile, BK=64, 8 waves
// (2Mx4N), wave tile 128x64. LDS: [slot0: A 32K | B 32K][slot1] = 128 KiB dbuf.
// K-loop unrolled 2 tiles/iter (literal slots); ds_reads via 8 precomputed
// per-lane base VGPRs + literal imms; stage addrs = 2 advancing pointers.
// vmcnt(4) once per K-tile; never 0 mid-loop. See R7 notes; unchanged.
template<int OUTMODE>
__global__ __launch_bounds__(512, 2) void gemm256(
    const _Float16* __restrict__ A, const _Float16* __restrict__ Bt,
    void* __restrict__ Cv, const float* __restrict__ Res,
    int M, int N, int K, int lda, int ldb, int ldc)
{
  extern __shared__ _Float16 smem[];   // [2][A:16384 | B:16384] elems

  // XCD-bijective remap
  const int gx = gridDim.x, gy = gridDim.y, gz = gridDim.z;
  int pid = (blockIdx.z * gy + blockIdx.y) * gx + blockIdx.x;
  const int qch = (gx * gy * gz) >> 3;
  int lid = (pid & 7) * qch + (pid >> 3);
  const int bx = lid % gx; lid /= gx;
  const int by = lid % gy; const int bz = lid / gy;

  const int tid  = threadIdx.x;
  const int lane = tid & 63;
  const int w    = tid >> 6;          // 0..7
  const int wm   = w >> 2;            // 0..1
  const int wn   = w & 3;             // 0..3
  const int l15  = lane & 15, q4 = lane >> 4;
  const int m0   = by * 256;
  const int n0   = bx * 256;
  const int KP   = K / gz;
  const int koff = bz * KP;
  const int NT   = KP >> 6;           // K-tiles of 64 (even)

  const int srow8  = lane >> 3;
  const int schunk = (((lane & 7) ^ (srow8 & 7)) << 3);
  const _Float16* AgP = A  + (size_t)(m0 + w * 8 + srow8) * lda + schunk + koff;
  const _Float16* BgP = Bt + (size_t)(n0 + w * 8 + srow8) * ldb + schunk + koff;
  const int ldsW = w * 512;

  const int c0 = ((q4 ^ (l15 & 7)) << 3);
  const int c1 = c0 ^ 32;
  const int arow_e = (wm * 128 + l15) * 64;
  const int brow_e = (wn * 64 + l15) * 64;
  const _Float16* aB[2][2];   // [slot][kk] — literal-indexed only
  const _Float16* bB[2][2];
  aB[0][0] = smem + arow_e + c0;          aB[0][1] = smem + arow_e + c1;
  aB[1][0] = aB[0][0] + 32768;            aB[1][1] = aB[0][1] + 32768;
  bB[0][0] = smem + 16384 + brow_e + c0;  bB[0][1] = smem + 16384 + brow_e + c1;
  bB[1][0] = bB[0][0] + 32768;            bB[1][1] = bB[0][1] + 32768;

  floatx4 acc[8][4];
#pragma unroll
  for (int i = 0; i < 8; ++i)
#pragma unroll
    for (int j = 0; j < 4; ++j)
#pragma unroll
      for (int r = 0; r < 4; ++r) acc[i][j][r] = 0.0f;

  half8 bf[2][4];
  half8 af0[4], af1[4];

#define STA(S, h, s, KO)                                                     \
  gl_lds16(AgP + (size_t)((h) * 128 + (s) * 64) * lda + (KO),                \
           smem + (S) * 32768 + (h) * 8192 + (s) * 4096 + ldsW)
#define STB(S, h, s, KO)                                                     \
  gl_lds16(BgP + (size_t)((h) * 128 + (s) * 64) * ldb + (KO),                \
           smem + (S) * 32768 + 16384 + (h) * 8192 + (s) * 4096 + ldsW)

#define SB0   __builtin_amdgcn_sched_barrier(0)
#define BARR  __builtin_amdgcn_s_barrier()
#define LGKM0 asm volatile("s_waitcnt lgkmcnt(0)" ::: "memory")

#define RD_B8(S)                                                             \
  { _Pragma("unroll")                                                        \
    for (int j = 0; j < 4; ++j) {                                            \
      bf[0][j] = *(const half8*)(bB[S][0] + j * 1024);                       \
      bf[1][j] = *(const half8*)(bB[S][1] + j * 1024);                       \
    } }
#define RD_A4(S, q, af)                                                      \
  { _Pragma("unroll")                                                        \
    for (int i2 = 0; i2 < 2; ++i2) {                                         \
      af[i2*2+0] = *(const half8*)(aB[S][0] + ((q)*2+i2) * 1024);            \
      af[i2*2+1] = *(const half8*)(aB[S][1] + ((q)*2+i2) * 1024);            \
    } }
#define MFMA_Q(q, af)                                                        \
  { _Pragma("unroll")                                                        \
    for (int kk = 0; kk < 2; ++kk)                                           \
      _Pragma("unroll")                                                      \
      for (int i2 = 0; i2 < 2; ++i2)                                         \
        _Pragma("unroll")                                                    \
        for (int j = 0; j < 4; ++j)                                          \
          acc[(q)*2+i2][j] = __builtin_amdgcn_mfma_f32_16x16x32_f16(         \
              af[i2*2+kk], bf[kk][j], acc[(q)*2+i2][j], 0, 0, 0);            \
  }

#define TILE(S, t, KOA, KOB)                                                 \
  {                                                                          \
    const bool s1 = (t) + 1 < NT, s2 = (t) + 2 < NT;                         \
    /* Ph1: all B + A-quad0 */                                               \
    RD_B8(S); RD_A4(S, 0, af0);                                              \
    if (s1) { STA((S) ^ 1, 0, 0, KOA); STA((S) ^ 1, 0, 1, KOA); }            \
    asm volatile("s_waitcnt lgkmcnt(8)" ::: "memory");                       \
    SB0; BARR; LGKM0; SB0;                                                   \
    __builtin_amdgcn_s_setprio(1); MFMA_Q(0, af0); __builtin_amdgcn_s_setprio(0); \
    SB0; BARR;                                                               \
    /* Ph2: A-quad1 */                                                       \
    RD_A4(S, 1, af1);                                                        \
    if (s1) { STA((S) ^ 1, 1, 0, KOA); STA((S) ^ 1, 1, 1, KOA); }            \
    SB0; BARR; LGKM0; SB0;                                                   \
    __builtin_amdgcn_s_setprio(1); MFMA_Q(1, af1); __builtin_amdgcn_s_setprio(0); \
    SB0; BARR;                                                               \
    /* Ph3: A-quad2 */                                                       \
    RD_A4(S, 2, af0);                                                        \
    if (s2) { STB(S, 0, 0, KOB); STB(S, 0, 1, KOB); }                        \
    SB0; BARR; LGKM0; SB0;                                                   \
    __builtin_amdgcn_s_setprio(1); MFMA_Q(2, af0); __builtin_amdgcn_s_setprio(0); \
    SB0; BARR;                                                               \
    /* Ph4: A-quad3 */                                                       \
    RD_A4(S, 3, af1);                                                        \
    if (s2) { STB(S, 1, 0, KOB); STB(S, 1, 1, KOB); }                        \
    SB0; BARR; LGKM0; SB0;                                                   \
    __builtin_amdgcn_s_setprio(1); MFMA_Q(3, af1); __builtin_amdgcn_s_setprio(0); \
    SB0;                                                                     \
    if (s2)      asm volatile("s_waitcnt vmcnt(4)" ::: "memory");            \
    else if (s1) asm volatile("s_waitcnt vmcnt(0)" ::: "memory");            \
    BARR;                                                                    \
  }

  STA(0, 0, 0, 0); STA(0, 0, 1, 0); STA(0, 1, 0, 0); STA(0, 1, 1, 0);
  STB(0, 0, 0, 0); STB(0, 0, 1, 0); STB(0, 1, 0, 0); STB(0, 1, 1, 0);
  if (NT > 1) {
    STB(1, 0, 0, 64); STB(1, 0, 1, 64); STB(1, 1, 0, 64); STB(1, 1, 1, 64);
    asm volatile("s_waitcnt vmcnt(4)" ::: "memory");
  } else {
    asm volatile("s_waitcnt vmcnt(0)" ::: "memory");
  }
  BARR;

  for (int t = 0; t < NT; t += 2) {
    TILE(0, t,     64, 128);
    TILE(1, t + 1, 128, 192);
    AgP += 128; BgP += 128;
  }

#undef STA
#undef STB
#undef SB0
#undef BARR
#undef LGKM0
#undef RD_B8
#undef RD_A4
#undef MFMA_Q
#undef TILE

  const int crow0 = m0 + wm * 128 + q4 * 4;
  const int ccol0 = n0 + wn * 64 + l15;
#pragma unroll
  for (int i = 0; i < 8; ++i)
#pragma unroll
    for (int j = 0; j < 4; ++j)
#pragma unroll
      for (int r = 0; r < 4; ++r) {
        size_t o = (size_t)(crow0 + i * 16 + r) * ldc + (ccol0 + j * 16);
        if constexpr (OUTMODE == 0)      ((_Float16*)Cv)[o] = (_Float16)acc[i][j][r];
        else if constexpr (OUTMODE == 1) ((float*)Cv)[o] = acc[i][j][r] + Res[o];
        else ((float*)Cv)[(size_t)bz * M * ldc + o] = acc[i][j][r];
      }
}

// ---------------- split-K reduce: out = p0 + p1 + res (all f32) -----------------
__global__ void addred_kernel(const float* __restrict__ parts, const float* __restrict__ res,
                              float* __restrict__ out) {
  size_t i = ((size_t)blockIdx.x * 256 + threadIdx.x) * 4;
  const size_t MN = (size_t)BT_ * D_;
  float4 a = *(const float4*)(parts + i);
  float4 b = *(const float4*)(parts + MN + i);
  float4 r = *(const float4*)(res + i);
  float4 o;
  o.x = a.x + b.x + r.x; o.y = a.y + b.y + r.y;
  o.z = a.z + b.z + r.z; o.w = a.w + b.w + r.w;
  *(float4*)(out + i) = o;
}

// ================================================================================
// Fused flash attention (causal, per (b,h) pair). Replaces scores+softmax+PV.
// Grid (32 pairs, 8): linear id % 8 = pair % 8 -> the 8 q-block-WGs of a pair
// share one XCD; ~4 resident pairs/XCD -> K/V (1 MB/pair) L2-resident.
// Each WG: 4 waves, wave w owns q-rows [w*32, w*32+32); processes q-blocks
// {y, 15-y} sequentially (balanced causal load: 17 KV tiles total).
// Q in A-frags (regs); K and V^T (vt) read global->B-frags (no staging).
// Online softmax in f32 (4x shfl_xor row-reduce over the 16 col-lanes).
// P: C-layout -> A-frag via LDS, rows are WAVE-PRIVATE -> no barriers at all.
__global__ __launch_bounds__(256, 2) void fattn_kernel(
    const _Float16* __restrict__ qkv, const _Float16* __restrict__ vt,
    _Float16* __restrict__ ob)
{
  __shared__ _Float16 Pl[128 * 136];   // row stride 136 f16 (pad vs bank conflicts)
  const int pr = blockIdx.x;           // pair 0..31
  const int yq = blockIdx.y;           // 0..7
  const int b = pr >> 4, h = pr & 15;
  const int lane = threadIdx.x & 63, w = threadIdx.x >> 6;
  const int l15 = lane & 15, q4 = lane >> 4;
  const float scale = 0.08838834764831845f;   // 1/sqrt(128)

  const _Float16* qg = qkv + (size_t)b * T_ * QKVLD_ + (size_t)h * HD_;
  const _Float16* kg = qg + D_;
  const _Float16* vg = vt + (size_t)pr * HD_ * T_;   // [d][t]
  _Float16* og = ob + (size_t)b * T_ * D_ + (size_t)h * HD_;

  for (int hf = 0; hf < 2; ++hf) {
    const int qb = hf ? (15 - yq) : yq;
    const int qrow0 = qb * 128 + w * 32;

    // Q fragments: lane holds Q[row=l15(+16i)][k=kf*32+q4*8 .. +8]
    half8 qf[2][4];
#pragma unroll
    for (int i = 0; i < 2; ++i)
#pragma unroll
      for (int kf = 0; kf < 4; ++kf)
        qf[i][kf] = *(const half8*)(qg + (size_t)(qrow0 + i * 16 + l15) * QKVLD_
                                       + kf * 32 + q4 * 8);

    floatx4 Oa[2][8];
    float m[8], l[8];
#pragma unroll
    for (int i = 0; i < 2; ++i)
#pragma unroll
      for (int j = 0; j < 8; ++j)
#pragma unroll
        for (int r = 0; r < 4; ++r) Oa[i][j][r] = 0.f;
#pragma unroll
    for (int z = 0; z < 8; ++z) { m[z] = -1e30f; l[z] = 0.f; }

    for (int kt = 0; kt <= qb; ++kt) {
      // ---- S = Q @ K^T ----
      floatx4 s[2][8];
#pragma unroll
      for (int i = 0; i < 2; ++i)
#pragma unroll
        for (int j = 0; j < 8; ++j)
#pragma unroll
          for (int r = 0; r < 4; ++r) s[i][j][r] = 0.f;
#pragma unroll
      for (int kf = 0; kf < 4; ++kf) {
#pragma unroll
        for (int j = 0; j < 8; ++j) {
          half8 kf8 = *(const half8*)(kg + (size_t)(kt * 128 + j * 16 + l15) * QKVLD_
                                         + kf * 32 + q4 * 8);
          s[0][j] = __builtin_amdgcn_mfma_f32_16x16x32_f16(qf[0][kf], kf8, s[0][j], 0, 0, 0);
          s[1][j] = __builtin_amdgcn_mfma_f32_16x16x32_f16(qf[1][kf], kf8, s[1][j], 0, 0, 0);
        }
      }
      // scale (f32, matches reference order)
#pragma unroll
      for (int i = 0; i < 2; ++i)
#pragma unroll
        for (int j = 0; j < 8; ++j)
#pragma unroll
          for (int r = 0; r < 4; ++r) s[i][j][r] *= scale;
      // causal mask (diagonal tile only): S element = [row w*32+i*16+q4*4+r][col j*16+l15]
      if (kt == qb) {
#pragma unroll
        for (int i = 0; i < 2; ++i)
#pragma unroll
          for (int j = 0; j < 8; ++j)
#pragma unroll
            for (int r = 0; r < 4; ++r)
              if (j * 16 + l15 > w * 32 + i * 16 + q4 * 4 + r) s[i][j][r] = -1e30f;
      }
      // ---- online softmax (per lane: 8 rows = 2i x 4r) ----
#pragma unroll
      for (int i = 0; i < 2; ++i)
#pragma unroll
        for (int r = 0; r < 4; ++r) {
          const int z = i * 4 + r;
          float pm = s[i][0][r];
#pragma unroll
          for (int j = 1; j < 8; ++j) pm = fmaxf(pm, s[i][j][r]);
          pm = fmaxf(pm, __shfl_xor(pm, 1));
          pm = fmaxf(pm, __shfl_xor(pm, 2));
          pm = fmaxf(pm, __shfl_xor(pm, 4));
          pm = fmaxf(pm, __shfl_xor(pm, 8));
          float mn = fmaxf(m[z], pm);
          float sc = __expf(m[z] - mn);
          m[z] = mn;
          float ls = 0.f;
#pragma unroll
          for (int j = 0; j < 8; ++j) {
            float e = __expf(s[i][j][r] - mn);
            s[i][j][r] = e;
            ls += e;
          }
          ls += __shfl_xor(ls, 1);
          ls += __shfl_xor(ls, 2);
          ls += __shfl_xor(ls, 4);
          ls += __shfl_xor(ls, 8);
          l[z] = l[z] * sc + ls;
#pragma unroll
          for (int jd = 0; jd < 8; ++jd) Oa[i][jd][r] *= sc;
        }
      // ---- P -> LDS (wave-private rows; no barrier needed) ----
#pragma unroll
      for (int i = 0; i < 2; ++i)
#pragma unroll
        for (int r = 0; r < 4; ++r) {
          _Float16* prow = &Pl[(size_t)(w * 32 + i * 16 + q4 * 4 + r) * 136 + l15];
#pragma unroll
          for (int j = 0; j < 8; ++j) prow[j * 16] = (_Float16)s[i][j][r];
        }
      // ---- O += P @ V  (P A-frags from LDS, V^T B-frags from vt) ----
#pragma unroll
      for (int ks = 0; ks < 4; ++ks) {
        half8 pf0 = *(const half8*)&Pl[(size_t)(w * 32 + l15) * 136 + ks * 32 + q4 * 8];
        half8 pf1 = *(const half8*)&Pl[(size_t)(w * 32 + 16 + l15) * 136 + ks * 32 + q4 * 8];
#pragma unroll
        for (int jd = 0; jd < 8; ++jd) {
          half8 vf = *(const half8*)(vg + (size_t)(jd * 16 + l15) * T_
                                        + kt * 128 + ks * 32 + q4 * 8);
          Oa[0][jd] = __builtin_amdgcn_mfma_f32_16x16x32_f16(pf0, vf, Oa[0][jd], 0, 0, 0);
          Oa[1][jd] = __builtin_amdgcn_mfma_f32_16x16x32_f16(pf1, vf, Oa[1][jd], 0, 0, 0);
        }
      }
    }
    // ---- epilogue: O / l -> ob ----
#pragma unroll
    for (int i = 0; i < 2; ++i)
#pragma unroll
      for (int r = 0; r < 4; ++r) {
        float inv = 1.0f / l[i * 4 + r];
        _Float16* orow = og + (size_t)(qrow0 + i * 16 + q4 * 4 + r) * D_;
#pragma unroll
        for (int jd = 0; jd < 8; ++jd)
          orow[jd * 16 + l15] = (_Float16)(Oa[i][jd][r] * inv);
      }
  }
}

// ---------------- RoPE on fused qkv (q at col 0, k at col D_) -------------------
__global__ void rope_kernel(_Float16* __restrict__ qkv, const void* __restrict__ pos) {
  int gid = blockIdx.x * 256 + threadIdx.x;   // BT_*H_*64 threads
  int d = gid & 63;
  int h = (gid >> 6) & 15;
  int bt = gid >> 10;
  const int* pi = (const int*)pos;
  long long pv = (pi[1] == 0 && pi[2] == 1) ? ((const long long*)pos)[bt]
                                            : (long long)pi[bt];
  float inv = exp2f((float)d * -0.2076205059304601f);  // 10000^(-d/64)
  float ang = (float)pv * inv;
  float s, c;
  sincosf(ang, &s, &c);
  size_t base = (size_t)bt * QKVLD_ + (size_t)h * HD_ + d;
  _Float16* q = qkv;
  _Float16* k = qkv + D_;
  float x1v = (float)q[base], x2v = (float)q[base + 64];
  q[base]      = (_Float16)(x1v * c - x2v * s);
  q[base + 64] = (_Float16)(x2v * c + x1v * s);
  x1v = (float)k[base]; x2v = (float)k[base + 64];
  k[base]      = (_Float16)(x1v * c - x2v * s);
  k[base + 64] = (_Float16)(x2v * c + x1v * s);
}

// ---------------- v[b][t][...] (ld stride) -> vt[(b*H+h)][d][t] -----------------
__global__ void vtrans_kernel(const _Float16* __restrict__ v, _Float16* __restrict__ vt,
                              int ld) {
  __shared__ _Float16 tile[32][33];
  int t0 = blockIdx.x * 32, d0 = blockIdx.y * 32, bh = blockIdx.z;
  int b = bh >> 4, h = bh & 15;
  int tx = threadIdx.x, ty = threadIdx.y;   // 32 x 8
  const _Float16* vb = v + (size_t)b * T_ * ld + (size_t)h * HD_;
#pragma unroll
  for (int r = 0; r < 32; r += 8)
    tile[ty + r][tx] = vb[(size_t)(t0 + ty + r) * ld + d0 + tx];
  __syncthreads();
  _Float16* vo = vt + ((size_t)bh * HD_ + d0) * T_ + t0;
#pragma unroll
  for (int r = 0; r < 32; r += 8)
    vo[(size_t)(ty + r) * T_ + tx] = tile[tx][ty + r];
}

// ---------------- hu = silu(gate) * up  (written over gate) ---------------------
__global__ void silumul_kernel(_Float16* __restrict__ gate, const _Float16* __restrict__ up) {
  size_t idx = ((size_t)blockIdx.x * 256 + threadIdx.x) * 8;
  uint4 gr = *(const uint4*)(gate + idx);
  uint4 ur = *(const uint4*)(up + idx);
  const _Float16* gh = (const _Float16*)&gr;
  const _Float16* uh = (const _Float16*)&ur;
  _Float16 t[8] __attribute__((aligned(16)));
#pragma unroll
  for (int l = 0; l < 8; l++) {
    float x = (float)gh[l];
    float s = x / (1.0f + __expf(-x));
    t[l] = (_Float16)(s * (float)uh[l]);
  }
  *(uint4*)(gate + idx) = *(const uint4*)t;
}

// ================================================================================
extern "C" void kernel_launch(void* const* d_in, const int* in_sizes, int n_in,
                              void* d_out, int out_size, void* d_ws, size_t ws_size,
                              hipStream_t stream) {
  (void)in_sizes; (void)n_in; (void)out_size;
  const float* x   = (const float*)d_in[0];
  const void*  pos = d_in[1];
  const float* W[7] = { (const float*)d_in[2], (const float*)d_in[3],
                        (const float*)d_in[4], (const float*)d_in[5],
                        (const float*)d_in[6], (const float*)d_in[7],
                        (const float*)d_in[8] };              // q k v o g u d
  const float* g1  = (const float*)d_in[9];
  const float* g2  = (const float*)d_in[10];
  float* out = (float*)d_out;

  const int wk[7] = { D_, D_, D_, D_, D_, D_, FF_ };
  const int wn[7] = { D_, D_, D_, D_, FF_, FF_, D_ };

  char* p = (char*)d_ws;
  auto carve = [&](size_t bytes) { char* r = p; p += (bytes + 255) & ~(size_t)255; return r; };

  _Float16* scratch = (_Float16*)carve((size_t)64 * 1024 * 1024);  // gate / Wo parts
  const size_t FLAT_NEED = (size_t)336 * 1024 * 1024;
  bool flat = ws_size >= FLAT_NEED;
  _Float16* w16[7];
  if (flat) {
    // q,k,v carved contiguously -> fused QKV weight matrix [6144][2048]
    for (int i = 0; i < 7; i++) w16[i] = (_Float16*)carve((size_t)wk[i] * wn[i] * 2);
  } else {
    _Float16* wslot = (_Float16*)carve((size_t)D_ * FF_ * 2);      // 32 MB slot
    w16[0] = wslot;
    w16[1] = wslot + (size_t)D_ * D_;
    w16[2] = wslot + (size_t)2 * D_ * D_;
    w16[3] = w16[4] = w16[5] = w16[6] = wslot;
  }
  _Float16* qkv = (_Float16*)carve((size_t)BT_ * QKVLD_ * 2);  // 48 MB
  _Float16* ob  = (_Float16*)carve((size_t)BT_ * D_ * 2);      // 16 MB (contig after qkv)
  _Float16* xn  = (_Float16*)carve((size_t)BT_ * D_ * 2);      // 16 MB; later: hb
  _Float16* vt  = (_Float16*)carve((size_t)BT_ * D_ * 2);      // 16 MB
  float*    x1  = (float*)   carve((size_t)BT_ * D_ * 4);      // 32 MB
  _Float16* gate = scratch;      // 64 MB region
  _Float16* up   = qkv;          // spans qkv(48)+ob(16): both dead after Wo GEMM
  _Float16* hb   = xn;
  float* oparts = (float*)scratch; // Wo split-K partials (2 x 32 MB)
  float* dparts = (float*)qkv;     // Wd split-K partials (2 x 32 MB); up dead by then

  dim3 b328(32, 8);
  auto conv = [&](int i) {
    wconv_kernel<<<dim3(wn[i] / 32, wk[i] / 64), b328, 0, stream>>>(W[i], w16[i], wk[i], wn[i]);
  };
  if (flat) for (int i = 0; i < 7; i++) conv(i);

  // xn = rmsnorm(x, g1)
  rmsnorm_kernel<<<BT_, 256, 0, stream>>>(x, g1, xn);

  // fused qkv projection: [BT][6144] = xn @ [Wq;Wk;Wv]^T   (384 WGs)
  if (!flat) { conv(0); conv(1); conv(2); }
  gemm256<0><<<dim3(QKVLD_ / 256, BT_ / 256, 1), 512, 131072, stream>>>(
      xn, w16[0], qkv, nullptr, BT_, QKVLD_, D_, D_, D_, QKVLD_);

  // rope(q, k) in fused layout
  rope_kernel<<<(BT_ * H_ * 64) / 256, 256, 0, stream>>>(qkv, pos);

  // v transpose per head: vt[(b*H+h)][d][t]
  vtrans_kernel<<<dim3(T_ / 32, HD_ / 32, NP_), b328, 0, stream>>>(qkv + 2 * D_, vt, QKVLD_);

  // fused flash attention: ob = softmax(QK^T/sqrt(d), causal) @ V
  fattn_kernel<<<dim3(NP_, 8), 256, 0, stream>>>(qkv, vt, ob);

  // x1 = x + o @ Wo : split-K=2 partials (256 WGs) + reduce
  if (!flat) conv(3);
  gemm256<2><<<dim3(D_ / 256, BT_ / 256, 2), 512, 131072, stream>>>(
      ob, w16[3], oparts, nullptr, BT_, D_, D_, D_, D_, D_);
  addred_kernel<<<(BT_ * D_ / 4) / 256, 256, 0, stream>>>(oparts, x, x1);

  // h = rmsnorm(x1, g2)
  rmsnorm_kernel<<<BT_, 256, 0, stream>>>(x1, g2, hb);

  // gate = h @ Wg ; up = h @ Wu   (512 WGs each)
  if (!flat) conv(4);
  gemm256<0><<<dim3(FF_ / 256, BT_ / 256, 1), 512, 131072, stream>>>(
      hb, w16[4], gate, nullptr, BT_, FF_, D_, D_, D_, FF_);
  if (!flat) conv(5);
  gemm256<0><<<dim3(FF_ / 256, BT_ / 256, 1), 512, 131072, stream>>>(
      hb, w16[5], up, nullptr, BT_, FF_, D_, D_, D_, FF_);

  // hu = silu(gate) * up  (in gate)
  silumul_kernel<<<(BT_ * FF_ / 8) / 256, 256, 0, stream>>>(gate, up);

  // Wd split-K=2: partials = hu @ Wd (per half-K), then out = p0 + p1 + x1
  if (!flat) conv(6);
  gemm256<2><<<dim3(D_ / 256, BT_ / 256, 2), 512, 131072, stream>>>(
      gate, w16[6], dparts, nullptr, BT_, D_, FF_, FF_, FF_, D_);
  addred_kernel<<<(BT_ * D_ / 4) / 256, 256, 0, stream>>>(dparts, x1, out);
}

// Round 9
// 1134.146 us; speedup vs baseline: 1.1697x; 1.0392x over previous
//
#include <hip/hip_runtime.h>
#include <cstdint>

#define D_  2048
#define H_  16
#define HD_ 128
#define FF_ 8192
#define T_  2048
#define B_  2
#define BT_ (B_*T_)
#define NP_ (B_*H_)        // 32 (b,h) pairs
#define QKVLD_ (3*D_)      // fused qkv row stride (6144)

typedef __attribute__((ext_vector_type(8))) _Float16 half8;
typedef __attribute__((ext_vector_type(4))) float   floatx4;

// async global->LDS, 16B per lane; LDS dest = wave-uniform base + lane*16
__device__ __forceinline__ void gl_lds16(const void* g, void* l) {
  __builtin_amdgcn_global_load_lds(
      (const __attribute__((address_space(1))) void*)(uintptr_t)g,
      (__attribute__((address_space(3))) void*)(uintptr_t)l,
      16, 0, 0);
}

// ---------------- weight convert + transpose: W[K][N] f32 -> Wt[N][K] f16 ----
__global__ void wconv_kernel(const float* __restrict__ W, _Float16* __restrict__ Wt,
                             int K, int N) {
  __shared__ float tile[64][33];
  int n0 = blockIdx.x * 32, k0 = blockIdx.y * 64;
  int tx = threadIdx.x, ty = threadIdx.y;   // 32 x 8
#pragma unroll
  for (int r = 0; r < 64; r += 8)
    tile[ty + r][tx] = W[(size_t)(k0 + ty + r) * N + n0 + tx];
  __syncthreads();
#pragma unroll
  for (int r = 0; r < 32; r += 8) {
    float a = tile[tx * 2][ty + r], b = tile[tx * 2 + 1][ty + r];
    union { _Float16 h[2]; unsigned u; } cv;
    cv.h[0] = (_Float16)a; cv.h[1] = (_Float16)b;
    ((unsigned*)(Wt + (size_t)(n0 + ty + r) * K + k0))[tx] = cv.u;
  }
}

// ---------------- rmsnorm: fp32 row -> fp16 row --------------------------------
__global__ void rmsnorm_kernel(const float* __restrict__ x, const float* __restrict__ g,
                               _Float16* __restrict__ out) {
  int row = blockIdx.x, tid = threadIdx.x;
  const float4* xr = (const float4*)(x + (size_t)row * D_);
  float4 v1 = xr[tid], v2 = xr[tid + 256];
  float ss = v1.x*v1.x + v1.y*v1.y + v1.z*v1.z + v1.w*v1.w
           + v2.x*v2.x + v2.y*v2.y + v2.z*v2.z + v2.w*v2.w;
  __shared__ float red[256];
  red[tid] = ss; __syncthreads();
  for (int s = 128; s > 0; s >>= 1) { if (tid < s) red[tid] += red[tid + s]; __syncthreads(); }
  float rs = rsqrtf(red[0] * (1.0f / D_) + 1e-6f);
  float4 ga = ((const float4*)g)[tid], gb = ((const float4*)g)[tid + 256];
  _Float16* orow = out + (size_t)row * D_;
  _Float16 t[4] __attribute__((aligned(8)));
  t[0] = (_Float16)(v1.x * rs * ga.x);
  t[1] = (_Float16)(v1.y * rs * ga.y);
  t[2] = (_Float16)(v1.z * rs * ga.z);
  t[3] = (_Float16)(v1.w * rs * ga.w);
  *(uint2*)(orow + tid * 4) = *(const uint2*)t;
  t[0] = (_Float16)(v2.x * rs * gb.x);
  t[1] = (_Float16)(v2.y * rs * gb.y);
  t[2] = (_Float16)(v2.z * rs * gb.z);
  t[3] = (_Float16)(v2.w * rs * gb.w);
  *(uint2*)(orow + (tid + 256) * 4) = *(const uint2*)t;
}

// ================================================================================
// 8-phase GEMM (m201 schedule), C = A @ Bt^T. 256x256 tile, BK=64, 8 waves
// (2Mx4N), wave tile 128x64. LDS: [slot0: A 32K | B 32K][slot1] = 128 KiB dbuf.
// K-loop unrolled 2 tiles/iter (literal slots); ds_reads via 8 precomputed
// per-lane base VGPRs + literal imms; stage addrs = 2 advancing pointers.
// vmcnt(4) once per K-tile; never 0 mid-loop. See R7 notes; unchanged.
template<int OUTMODE>
__global__ __launch_bounds__(512, 2) void gemm256(
    const _Float16* __restrict__ A, const _Float16* __restrict__ Bt,
    void* __restrict__ Cv, const float* __restrict__ Res,
    int M, int N, int K, int lda, int ldb, int ldc)
{
  extern __shared__ _Float16 smem[];   // [2][A:16384 | B:16384] elems

  // XCD-bijective remap
  const int gx = gridDim.x, gy = gridDim.y, gz = gridDim.z;
  int pid = (blockIdx.z * gy + blockIdx.y) * gx + blockIdx.x;
  const int qch = (gx * gy * gz) >> 3;
  int lid = (pid & 7) * qch + (pid >> 3);
  const int bx = lid % gx; lid /= gx;
  const int by = lid % gy; const int bz = lid / gy;

  const int tid  = threadIdx.x;
  const int lane = tid & 63;
  const int w    = tid >> 6;          // 0..7
  const int wm   = w >> 2;            // 0..1
  const int wn   = w & 3;             // 0..3
  const int l15  = lane & 15, q4 = lane >> 4;
  const int m0   = by * 256;
  const int n0   = bx * 256;
  const int KP   = K / gz;
  const int koff = bz * KP;
  const int NT   = KP >> 6;           // K-tiles of 64 (even)

  const int srow8  = lane >> 3;
  const int schunk = (((lane & 7) ^ (srow8 & 7)) << 3);
  const _Float16* AgP = A  + (size_t)(m0 + w * 8 + srow8) * lda + schunk + koff;
  const _Float16* BgP = Bt + (size_t)(n0 + w * 8 + srow8) * ldb + schunk + koff;
  const int ldsW = w * 512;

  const int c0 = ((q4 ^ (l15 & 7)) << 3);
  const int c1 = c0 ^ 32;
  const int arow_e = (wm * 128 + l15) * 64;
  const int brow_e = (wn * 64 + l15) * 64;
  const _Float16* aB[2][2];   // [slot][kk] — literal-indexed only
  const _Float16* bB[2][2];
  aB[0][0] = smem + arow_e + c0;          aB[0][1] = smem + arow_e + c1;
  aB[1][0] = aB[0][0] + 32768;            aB[1][1] = aB[0][1] + 32768;
  bB[0][0] = smem + 16384 + brow_e + c0;  bB[0][1] = smem + 16384 + brow_e + c1;
  bB[1][0] = bB[0][0] + 32768;            bB[1][1] = bB[0][1] + 32768;

  floatx4 acc[8][4];
#pragma unroll
  for (int i = 0; i < 8; ++i)
#pragma unroll
    for (int j = 0; j < 4; ++j)
#pragma unroll
      for (int r = 0; r < 4; ++r) acc[i][j][r] = 0.0f;

  half8 bf[2][4];
  half8 af0[4], af1[4];

#define STA(S, h, s, KO)                                                     \
  gl_lds16(AgP + (size_t)((h) * 128 + (s) * 64) * lda + (KO),                \
           smem + (S) * 32768 + (h) * 8192 + (s) * 4096 + ldsW)
#define STB(S, h, s, KO)                                                     \
  gl_lds16(BgP + (size_t)((h) * 128 + (s) * 64) * ldb + (KO),                \
           smem + (S) * 32768 + 16384 + (h) * 8192 + (s) * 4096 + ldsW)

#define SB0   __builtin_amdgcn_sched_barrier(0)
#define BARR  __builtin_amdgcn_s_barrier()
#define LGKM0 asm volatile("s_waitcnt lgkmcnt(0)" ::: "memory")

#define RD_B8(S)                                                             \
  { _Pragma("unroll")                                                        \
    for (int j = 0; j < 4; ++j) {                                            \
      bf[0][j] = *(const half8*)(bB[S][0] + j * 1024);                       \
      bf[1][j] = *(const half8*)(bB[S][1] + j * 1024);                       \
    } }
#define RD_A4(S, q, af)                                                      \
  { _Pragma("unroll")                                                        \
    for (int i2 = 0; i2 < 2; ++i2) {                                         \
      af[i2*2+0] = *(const half8*)(aB[S][0] + ((q)*2+i2) * 1024);            \
      af[i2*2+1] = *(const half8*)(aB[S][1] + ((q)*2+i2) * 1024);            \
    } }
#define MFMA_Q(q, af)                                                        \
  { _Pragma("unroll")                                                        \
    for (int kk = 0; kk < 2; ++kk)                                           \
      _Pragma("unroll")                                                      \
      for (int i2 = 0; i2 < 2; ++i2)                                         \
        _Pragma("unroll")                                                    \
        for (int j = 0; j < 4; ++j)                                          \
          acc[(q)*2+i2][j] = __builtin_amdgcn_mfma_f32_16x16x32_f16(         \
              af[i2*2+kk], bf[kk][j], acc[(q)*2+i2][j], 0, 0, 0);            \
  }

#define TILE(S, t, KOA, KOB)                                                 \
  {                                                                          \
    const bool s1 = (t) + 1 < NT, s2 = (t) + 2 < NT;                         \
    /* Ph1: all B + A-quad0 */                                               \
    RD_B8(S); RD_A4(S, 0, af0);                                              \
    if (s1) { STA((S) ^ 1, 0, 0, KOA); STA((S) ^ 1, 0, 1, KOA); }            \
    asm volatile("s_waitcnt lgkmcnt(8)" ::: "memory");                       \
    SB0; BARR; LGKM0; SB0;                                                   \
    __builtin_amdgcn_s_setprio(1); MFMA_Q(0, af0); __builtin_amdgcn_s_setprio(0); \
    SB0; BARR;                                                               \
    /* Ph2: A-quad1 */                                                       \
    RD_A4(S, 1, af1);                                                        \
    if (s1) { STA((S) ^ 1, 1, 0, KOA); STA((S) ^ 1, 1, 1, KOA); }            \
    SB0; BARR; LGKM0; SB0;                                                   \
    __builtin_amdgcn_s_setprio(1); MFMA_Q(1, af1); __builtin_amdgcn_s_setprio(0); \
    SB0; BARR;                                                               \
    /* Ph3: A-quad2 */                                                       \
    RD_A4(S, 2, af0);                                                        \
    if (s2) { STB(S, 0, 0, KOB); STB(S, 0, 1, KOB); }                        \
    SB0; BARR; LGKM0; SB0;                                                   \
    __builtin_amdgcn_s_setprio(1); MFMA_Q(2, af0); __builtin_amdgcn_s_setprio(0); \
    SB0; BARR;                                                               \
    /* Ph4: A-quad3 */                                                       \
    RD_A4(S, 3, af1);                                                        \
    if (s2) { STB(S, 1, 0, KOB); STB(S, 1, 1, KOB); }                        \
    SB0; BARR; LGKM0; SB0;                                                   \
    __builtin_amdgcn_s_setprio(1); MFMA_Q(3, af1); __builtin_amdgcn_s_setprio(0); \
    SB0;                                                                     \
    if (s2)      asm volatile("s_waitcnt vmcnt(4)" ::: "memory");            \
    else if (s1) asm volatile("s_waitcnt vmcnt(0)" ::: "memory");            \
    BARR;                                                                    \
  }

  STA(0, 0, 0, 0); STA(0, 0, 1, 0); STA(0, 1, 0, 0); STA(0, 1, 1, 0);
  STB(0, 0, 0, 0); STB(0, 0, 1, 0); STB(0, 1, 0, 0); STB(0, 1, 1, 0);
  if (NT > 1) {
    STB(1, 0, 0, 64); STB(1, 0, 1, 64); STB(1, 1, 0, 64); STB(1, 1, 1, 64);
    asm volatile("s_waitcnt vmcnt(4)" ::: "memory");
  } else {
    asm volatile("s_waitcnt vmcnt(0)" ::: "memory");
  }
  BARR;

  for (int t = 0; t < NT; t += 2) {
    TILE(0, t,     64, 128);
    TILE(1, t + 1, 128, 192);
    AgP += 128; BgP += 128;
  }

#undef STA
#undef STB
#undef SB0
#undef BARR
#undef LGKM0
#undef RD_B8
#undef RD_A4
#undef MFMA_Q
#undef TILE

  const int crow0 = m0 + wm * 128 + q4 * 4;
  const int ccol0 = n0 + wn * 64 + l15;
#pragma unroll
  for (int i = 0; i < 8; ++i)
#pragma unroll
    for (int j = 0; j < 4; ++j)
#pragma unroll
      for (int r = 0; r < 4; ++r) {
        size_t o = (size_t)(crow0 + i * 16 + r) * ldc + (ccol0 + j * 16);
        if constexpr (OUTMODE == 0)      ((_Float16*)Cv)[o] = (_Float16)acc[i][j][r];
        else if constexpr (OUTMODE == 1) ((float*)Cv)[o] = acc[i][j][r] + Res[o];
        else ((float*)Cv)[(size_t)bz * M * ldc + o] = acc[i][j][r];
      }
}

// ---------------- split-K reduce: out = p0 + p1 + res (all f32) -----------------
__global__ void addred_kernel(const float* __restrict__ parts, const float* __restrict__ res,
                              float* __restrict__ out) {
  size_t i = ((size_t)blockIdx.x * 256 + threadIdx.x) * 4;
  const size_t MN = (size_t)BT_ * D_;
  float4 a = *(const float4*)(parts + i);
  float4 b = *(const float4*)(parts + MN + i);
  float4 r = *(const float4*)(res + i);
  float4 o;
  o.x = a.x + b.x + r.x; o.y = a.y + b.y + r.y;
  o.z = a.z + b.z + r.z; o.w = a.w + b.w + r.w;
  *(float4*)(out + i) = o;
}

// ================================================================================
// Fused flash attention (causal). One q-block (128 rows) per WG; grid (32, 16)
// = 512 WGs = 2 blocks/CU (all co-resident; 2 waves/SIMD for latency hiding).
// yq->qb map pairs CU-sharing blocks to equal causal work (sum = 17 KV tiles).
// XCD locality: linear id % 8 = pair % 8 (32 % 8 == 0).
// Wave w owns q-rows [w*32, w*32+32). Q in regs; K/V read global->regs in
// 8-wide DOUBLE-BUFFERED batches (k0/k1 over kf, v0/v1 over ks) so load
// latency overlaps MFMA; V ks=0 batch issued before softmax (independent).
// Online softmax f32 (4x shfl_xor over 16 col-lanes). P via wave-private LDS
// rows -> no barriers.
__global__ __launch_bounds__(256, 2) void fattn_kernel(
    const _Float16* __restrict__ qkv, const _Float16* __restrict__ vt,
    _Float16* __restrict__ ob)
{
  __shared__ _Float16 Pl[128 * 136];   // row stride 136 f16 (pad vs bank conflicts)
  const int pr = blockIdx.x;           // pair 0..31
  const int yq = blockIdx.y;           // 0..15
  const int qb = (yq < 8) ? yq : 23 - yq;   // CU-pair work balance
  const int b = pr >> 4, h = pr & 15;
  const int lane = threadIdx.x & 63, w = threadIdx.x >> 6;
  const int l15 = lane & 15, q4 = lane >> 4;
  const float scale = 0.08838834764831845f;   // 1/sqrt(128)

  const _Float16* qg = qkv + (size_t)b * T_ * QKVLD_ + (size_t)h * HD_;
  const _Float16* kg = qg + D_;
  const _Float16* vg = vt + (size_t)pr * HD_ * T_;   // [d][t]
  _Float16* og = ob + (size_t)b * T_ * D_ + (size_t)h * HD_;

  const int qrow0 = qb * 128 + w * 32;

  // Q fragments: lane holds Q[row=l15(+16i)][k=kf*32+q4*8 .. +8]
  half8 qf[2][4];
#pragma unroll
  for (int i = 0; i < 2; ++i)
#pragma unroll
    for (int kf = 0; kf < 4; ++kf)
      qf[i][kf] = *(const half8*)(qg + (size_t)(qrow0 + i * 16 + l15) * QKVLD_
                                     + kf * 32 + q4 * 8);

  floatx4 Oa[2][8];
  float m[8], l[8];
#pragma unroll
  for (int i = 0; i < 2; ++i)
#pragma unroll
    for (int j = 0; j < 8; ++j)
#pragma unroll
      for (int r = 0; r < 4; ++r) Oa[i][j][r] = 0.f;
#pragma unroll
  for (int z = 0; z < 8; ++z) { m[z] = -1e30f; l[z] = 0.f; }

  for (int kt = 0; kt <= qb; ++kt) {
    const _Float16* kb_ = kg + (size_t)(kt * 128 + l15) * QKVLD_ + q4 * 8;
    // ---- S = Q @ K^T, K in 8-wide double-buffered batches ----
    half8 k0[8], k1[8];
#pragma unroll
    for (int j = 0; j < 8; ++j)
      k0[j] = *(const half8*)(kb_ + (size_t)(j * 16) * QKVLD_);
    floatx4 s[2][8];
#pragma unroll
    for (int i = 0; i < 2; ++i)
#pragma unroll
      for (int j = 0; j < 8; ++j)
#pragma unroll
        for (int r = 0; r < 4; ++r) s[i][j][r] = 0.f;
#pragma unroll
    for (int kf = 0; kf < 4; ++kf) {
      if (kf < 3) {
#pragma unroll
        for (int j = 0; j < 8; ++j) {
          half8 nx = *(const half8*)(kb_ + (size_t)(j * 16) * QKVLD_ + (kf + 1) * 32);
          if (kf & 1) k0[j] = nx; else k1[j] = nx;
        }
      }
#pragma unroll
      for (int j = 0; j < 8; ++j) {
        half8 cur = (kf & 1) ? k1[j] : k0[j];
        s[0][j] = __builtin_amdgcn_mfma_f32_16x16x32_f16(qf[0][kf], cur, s[0][j], 0, 0, 0);
        s[1][j] = __builtin_amdgcn_mfma_f32_16x16x32_f16(qf[1][kf], cur, s[1][j], 0, 0, 0);
      }
    }
    // scale (f32, matches reference order)
#pragma unroll
    for (int i = 0; i < 2; ++i)
#pragma unroll
      for (int j = 0; j < 8; ++j)
#pragma unroll
        for (int r = 0; r < 4; ++r) s[i][j][r] *= scale;
    // causal mask (diagonal tile only)
    if (kt == qb) {
#pragma unroll
      for (int i = 0; i < 2; ++i)
#pragma unroll
        for (int j = 0; j < 8; ++j)
#pragma unroll
          for (int r = 0; r < 4; ++r)
            if (j * 16 + l15 > w * 32 + i * 16 + q4 * 4 + r) s[i][j][r] = -1e30f;
    }
    // ---- V ks=0 batch: independent of softmax, issue now ----
    const _Float16* vb_ = vg + (size_t)(l15) * T_ + kt * 128 + q4 * 8;
    half8 v0[8], v1[8];
#pragma unroll
    for (int jd = 0; jd < 8; ++jd)
      v0[jd] = *(const half8*)(vb_ + (size_t)(jd * 16) * T_);
    // ---- online softmax (per lane: 8 rows = 2i x 4r) ----
#pragma unroll
    for (int i = 0; i < 2; ++i)
#pragma unroll
      for (int r = 0; r < 4; ++r) {
        const int z = i * 4 + r;
        float pm = s[i][0][r];
#pragma unroll
        for (int j = 1; j < 8; ++j) pm = fmaxf(pm, s[i][j][r]);
        pm = fmaxf(pm, __shfl_xor(pm, 1));
        pm = fmaxf(pm, __shfl_xor(pm, 2));
        pm = fmaxf(pm, __shfl_xor(pm, 4));
        pm = fmaxf(pm, __shfl_xor(pm, 8));
        float mn = fmaxf(m[z], pm);
        float sc = __expf(m[z] - mn);
        m[z] = mn;
        float ls = 0.f;
#pragma unroll
        for (int j = 0; j < 8; ++j) {
          float e = __expf(s[i][j][r] - mn);
          s[i][j][r] = e;
          ls += e;
        }
        ls += __shfl_xor(ls, 1);
        ls += __shfl_xor(ls, 2);
        ls += __shfl_xor(ls, 4);
        ls += __shfl_xor(ls, 8);
        l[z] = l[z] * sc + ls;
#pragma unroll
        for (int jd = 0; jd < 8; ++jd) Oa[i][jd][r] *= sc;
      }
    // ---- P -> LDS (wave-private rows; no barrier needed) ----
#pragma unroll
    for (int i = 0; i < 2; ++i)
#pragma unroll
      for (int r = 0; r < 4; ++r) {
        _Float16* prow = &Pl[(size_t)(w * 32 + i * 16 + q4 * 4 + r) * 136 + l15];
#pragma unroll
        for (int j = 0; j < 8; ++j) prow[j * 16] = (_Float16)s[i][j][r];
      }
    // ---- O += P @ V, V double-buffered over ks ----
#pragma unroll
    for (int ks = 0; ks < 4; ++ks) {
      if (ks < 3) {
#pragma unroll
        for (int jd = 0; jd < 8; ++jd) {
          half8 nx = *(const half8*)(vb_ + (size_t)(jd * 16) * T_ + (ks + 1) * 32);
          if (ks & 1) v0[jd] = nx; else v1[jd] = nx;
        }
      }
      half8 pf0 = *(const half8*)&Pl[(size_t)(w * 32 + l15) * 136 + ks * 32 + q4 * 8];
      half8 pf1 = *(const half8*)&Pl[(size_t)(w * 32 + 16 + l15) * 136 + ks * 32 + q4 * 8];
#pragma unroll
      for (int jd = 0; jd < 8; ++jd) {
        half8 vf = (ks & 1) ? v1[jd] : v0[jd];
        Oa[0][jd] = __builtin_amdgcn_mfma_f32_16x16x32_f16(pf0, vf, Oa[0][jd], 0, 0, 0);
        Oa[1][jd] = __builtin_amdgcn_mfma_f32_16x16x32_f16(pf1, vf, Oa[1][jd], 0, 0, 0);
      }
    }
  }
  // ---- epilogue: O / l -> ob ----
#pragma unroll
  for (int i = 0; i < 2; ++i)
#pragma unroll
    for (int r = 0; r < 4; ++r) {
      float inv = 1.0f / l[i * 4 + r];
      _Float16* orow = og + (size_t)(qrow0 + i * 16 + q4 * 4 + r) * D_;
#pragma unroll
      for (int jd = 0; jd < 8; ++jd)
        orow[jd * 16 + l15] = (_Float16)(Oa[i][jd][r] * inv);
    }
}

// ---------------- RoPE on fused qkv (q at col 0, k at col D_) -------------------
__global__ void rope_kernel(_Float16* __restrict__ qkv, const void* __restrict__ pos) {
  int gid = blockIdx.x * 256 + threadIdx.x;   // BT_*H_*64 threads
  int d = gid & 63;
  int h = (gid >> 6) & 15;
  int bt = gid >> 10;
  const int* pi = (const int*)pos;
  long long pv = (pi[1] == 0 && pi[2] == 1) ? ((const long long*)pos)[bt]
                                            : (long long)pi[bt];
  float inv = exp2f((float)d * -0.2076205059304601f);  // 10000^(-d/64)
  float ang = (float)pv * inv;
  float s, c;
  sincosf(ang, &s, &c);
  size_t base = (size_t)bt * QKVLD_ + (size_t)h * HD_ + d;
  _Float16* q = qkv;
  _Float16* k = qkv + D_;
  float x1v = (float)q[base], x2v = (float)q[base + 64];
  q[base]      = (_Float16)(x1v * c - x2v * s);
  q[base + 64] = (_Float16)(x2v * c + x1v * s);
  x1v = (float)k[base]; x2v = (float)k[base + 64];
  k[base]      = (_Float16)(x1v * c - x2v * s);
  k[base + 64] = (_Float16)(x2v * c + x1v * s);
}

// ---------------- v[b][t][...] (ld stride) -> vt[(b*H+h)][d][t] -----------------
__global__ void vtrans_kernel(const _Float16* __restrict__ v, _Float16* __restrict__ vt,
                              int ld) {
  __shared__ _Float16 tile[32][33];
  int t0 = blockIdx.x * 32, d0 = blockIdx.y * 32, bh = blockIdx.z;
  int b = bh >> 4, h = bh & 15;
  int tx = threadIdx.x, ty = threadIdx.y;   // 32 x 8
  const _Float16* vb = v + (size_t)b * T_ * ld + (size_t)h * HD_;
#pragma unroll
  for (int r = 0; r < 32; r += 8)
    tile[ty + r][tx] = vb[(size_t)(t0 + ty + r) * ld + d0 + tx];
  __syncthreads();
  _Float16* vo = vt + ((size_t)bh * HD_ + d0) * T_ + t0;
#pragma unroll
  for (int r = 0; r < 32; r += 8)
    vo[(size_t)(ty + r) * T_ + tx] = tile[tx][ty + r];
}

// ---------------- hu = silu(gate) * up  (written over gate) ---------------------
__global__ void silumul_kernel(_Float16* __restrict__ gate, const _Float16* __restrict__ up) {
  size_t idx = ((size_t)blockIdx.x * 256 + threadIdx.x) * 8;
  uint4 gr = *(const uint4*)(gate + idx);
  uint4 ur = *(const uint4*)(up + idx);
  const _Float16* gh = (const _Float16*)&gr;
  const _Float16* uh = (const _Float16*)&ur;
  _Float16 t[8] __attribute__((aligned(16)));
#pragma unroll
  for (int l = 0; l < 8; l++) {
    float x = (float)gh[l];
    float s = x / (1.0f + __expf(-x));
    t[l] = (_Float16)(s * (float)uh[l]);
  }
  *(uint4*)(gate + idx) = *(const uint4*)t;
}

// ================================================================================
extern "C" void kernel_launch(void* const* d_in, const int* in_sizes, int n_in,
                              void* d_out, int out_size, void* d_ws, size_t ws_size,
                              hipStream_t stream) {
  (void)in_sizes; (void)n_in; (void)out_size;
  const float* x   = (const float*)d_in[0];
  const void*  pos = d_in[1];
  const float* W[7] = { (const float*)d_in[2], (const float*)d_in[3],
                        (const float*)d_in[4], (const float*)d_in[5],
                        (const float*)d_in[6], (const float*)d_in[7],
                        (const float*)d_in[8] };              // q k v o g u d
  const float* g1  = (const float*)d_in[9];
  const float* g2  = (const float*)d_in[10];
  float* out = (float*)d_out;

  const int wk[7] = { D_, D_, D_, D_, D_, D_, FF_ };
  const int wn[7] = { D_, D_, D_, D_, FF_, FF_, D_ };

  char* p = (char*)d_ws;
  auto carve = [&](size_t bytes) { char* r = p; p += (bytes + 255) & ~(size_t)255; return r; };

  _Float16* scratch = (_Float16*)carve((size_t)64 * 1024 * 1024);  // gate / Wo parts
  const size_t FLAT_NEED = (size_t)336 * 1024 * 1024;
  bool flat = ws_size >= FLAT_NEED;
  _Float16* w16[7];
  if (flat) {
    // q,k,v carved contiguously -> fused QKV weight matrix [6144][2048]
    for (int i = 0; i < 7; i++) w16[i] = (_Float16*)carve((size_t)wk[i] * wn[i] * 2);
  } else {
    _Float16* wslot = (_Float16*)carve((size_t)D_ * FF_ * 2);      // 32 MB slot
    w16[0] = wslot;
    w16[1] = wslot + (size_t)D_ * D_;
    w16[2] = wslot + (size_t)2 * D_ * D_;
    w16[3] = w16[4] = w16[5] = w16[6] = wslot;
  }
  _Float16* qkv = (_Float16*)carve((size_t)BT_ * QKVLD_ * 2);  // 48 MB
  _Float16* ob  = (_Float16*)carve((size_t)BT_ * D_ * 2);      // 16 MB (contig after qkv)
  _Float16* xn  = (_Float16*)carve((size_t)BT_ * D_ * 2);      // 16 MB; later: hb
  _Float16* vt  = (_Float16*)carve((size_t)BT_ * D_ * 2);      // 16 MB
  float*    x1  = (float*)   carve((size_t)BT_ * D_ * 4);      // 32 MB
  _Float16* gate = scratch;      // 64 MB region
  _Float16* up   = qkv;          // spans qkv(48)+ob(16): both dead after Wo GEMM
  _Float16* hb   = xn;
  float* oparts = (float*)scratch; // Wo split-K partials (2 x 32 MB)
  float* dparts = (float*)qkv;     // Wd split-K partials (2 x 32 MB); up dead by then

  dim3 b328(32, 8);
  auto conv = [&](int i) {
    wconv_kernel<<<dim3(wn[i] / 32, wk[i] / 64), b328, 0, stream>>>(W[i], w16[i], wk[i], wn[i]);
  };
  if (flat) for (int i = 0; i < 7; i++) conv(i);

  // xn = rmsnorm(x, g1)
  rmsnorm_kernel<<<BT_, 256, 0, stream>>>(x, g1, xn);

  // fused qkv projection: [BT][6144] = xn @ [Wq;Wk;Wv]^T   (384 WGs)
  if (!flat) { conv(0); conv(1); conv(2); }
  gemm256<0><<<dim3(QKVLD_ / 256, BT_ / 256, 1), 512, 131072, stream>>>(
      xn, w16[0], qkv, nullptr, BT_, QKVLD_, D_, D_, D_, QKVLD_);

  // rope(q, k) in fused layout
  rope_kernel<<<(BT_ * H_ * 64) / 256, 256, 0, stream>>>(qkv, pos);

  // v transpose per head: vt[(b*H+h)][d][t]
  vtrans_kernel<<<dim3(T_ / 32, HD_ / 32, NP_), b328, 0, stream>>>(qkv + 2 * D_, vt, QKVLD_);

  // fused flash attention: ob = softmax(QK^T/sqrt(d), causal) @ V  (512 WGs)
  fattn_kernel<<<dim3(NP_, 16), 256, 0, stream>>>(qkv, vt, ob);

  // x1 = x + o @ Wo : split-K=2 partials (256 WGs) + reduce
  if (!flat) conv(3);
  gemm256<2><<<dim3(D_ / 256, BT_ / 256, 2), 512, 131072, stream>>>(
      ob, w16[3], oparts, nullptr, BT_, D_, D_, D_, D_, D_);
  addred_kernel<<<(BT_ * D_ / 4) / 256, 256, 0, stream>>>(oparts, x, x1);

  // h = rmsnorm(x1, g2)
  rmsnorm_kernel<<<BT_, 256, 0, stream>>>(x1, g2, hb);

  // gate = h @ Wg ; up = h @ Wu   (512 WGs each)
  if (!flat) conv(4);
  gemm256<0><<<dim3(FF_ / 256, BT_ / 256, 1), 512, 131072, stream>>>(
      hb, w16[4], gate, nullptr, BT_, FF_, D_, D_, D_, FF_);
  if (!flat) conv(5);
  gemm256<0><<<dim3(FF_ / 256, BT_ / 256, 1), 512, 131072, stream>>>(
      hb, w16[5], up, nullptr, BT_, FF_, D_, D_, D_, FF_);

  // hu = silu(gate) * up  (in gate)
  silumul_kernel<<<(BT_ * FF_ / 8) / 256, 256, 0, stream>>>(gate, up);

  // Wd split-K=2: partials = hu @ Wd (per half-K), then out = p0 + p1 + x1
  if (!flat) conv(6);
  gemm256<2><<<dim3(D_ / 256, BT_ / 256, 2), 512, 131072, stream>>>(
      gate, w16[6], dparts, nullptr, BT_, D_, FF_, FF_, FF_, D_);
  addred_kernel<<<(BT_ * D_ / 4) / 256, 256, 0, stream>>>(dparts, x1, out);
}